// Round 10
// baseline (568.533 us; speedup 1.0000x reference)
//
#include <hip/hip_runtime.h>
#include <hip/hip_bf16.h>
#include <stdint.h>

// ---------------- static problem sizes ----------------
#define BB    32
#define NPER  1024
#define NTOT  32768
#define DD    128
#define HH    4
#define HD    32
#define LL    3
#define DFF   2048
#define INDIM 64
#define QKSCALE 0.17677669529663687f

typedef unsigned short u16;
typedef short bf16x8 __attribute__((ext_vector_type(8)));   // 8 bf16 (4 VGPRs)
typedef float f32x4 __attribute__((ext_vector_type(4)));
typedef float f32x16 __attribute__((ext_vector_type(16)));  // 32x32 MFMA acc

// address-space casts for global_load_lds (direct global->LDS DMA)
#define AS_GLOBAL(p) ((const __attribute__((address_space(1))) void*)(p))
#define AS_LDS(p)    ((__attribute__((address_space(3))) void*)(p))

__device__ __forceinline__ float bf2f(u16 v){
  unsigned u = ((unsigned)v) << 16; float f; __builtin_memcpy(&f, &u, 4); return f;
}
__device__ __forceinline__ u16 f2bf(float f){
  unsigned u; __builtin_memcpy(&u, &f, 4);
  unsigned lsb = (u >> 16) & 1u;
  u += 0x7fffu + lsb;              // round-to-nearest-even
  return (u16)(u >> 16);
}

// ---------------- workspace layout (bytes) ----------------
constexpr size_t OFF_FLAG   = 0;
constexpr size_t OFF_STARTS = 256;
constexpr size_t OFF_BIN    = 1024;
constexpr size_t OFF_BQKV   = OFF_BIN   + 128*4;
constexpr size_t OFF_BO     = OFF_BQKV  + 1152*4;
constexpr size_t OFF_B1     = OFF_BO    + 384*4;
constexpr size_t OFF_B2     = OFF_B1    + 6144*4;
constexpr size_t OFF_LN1G   = OFF_B2    + 384*4;
constexpr size_t OFF_LN1B   = OFF_LN1G  + 384*4;
constexpr size_t OFF_LN2G   = OFF_LN1B  + 384*4;
constexpr size_t OFF_LN2B   = OFF_LN2G  + 384*4;
constexpr size_t OFF_XB     = 40960;
constexpr size_t OFF_WINB   = OFF_XB    + (size_t)2097152*2;
constexpr size_t OFF_WQKVB  = OFF_WINB  + (size_t)8192*2;
constexpr size_t OFF_WOB    = OFF_WQKVB + (size_t)147456*2;
constexpr size_t OFF_W1B    = OFF_WOB   + (size_t)49152*2;
constexpr size_t OFF_W2B    = OFF_W1B   + (size_t)786432*2;
constexpr size_t OFF_CUR    = OFF_W2B   + (size_t)786432*2;
constexpr size_t OFF_TMP    = OFF_CUR   + (size_t)4194304*4;
constexpr size_t OFF_CURB   = OFF_TMP   + (size_t)4194304*4;
constexpr size_t OFF_QKVB   = OFF_CURB  + (size_t)4194304*2;
constexpr size_t OFF_ATTNOB = OFF_QKVB  + (size_t)12582912*2;
constexpr size_t OFF_ACTB   = OFF_ATTNOB+ (size_t)4194304*2;     // (unused now)
constexpr size_t OFF_MASK   = OFF_ACTB  + (size_t)16777216*2;
constexpr size_t OFF_VT     = OFF_MASK  + (size_t)NTOT*4;
constexpr size_t OFF_RED    = OFF_VT    + (size_t)4096*1024*2;
constexpr size_t OFF_CNT    = OFF_RED   + (size_t)32*8*128*4;

// ---------------- dtype detection ----------------
__device__ __forceinline__ int plaus(unsigned bits){
  if ((bits << 1) == 0u) return 1;
  unsigned e = (bits >> 23) & 0xFFu;
  return (e >= 100u && e <= 140u) ? 1 : 0;
}
__global__ void detect_kernel(const unsigned* __restrict__ x, int* __restrict__ flag){
  __shared__ int red[256];
  int t = threadIdx.x, c = 0;
  for (int i = t; i < 2048; i += 256){
    unsigned w = x[i];
    c += (plaus(w << 16) & plaus(w & 0xFFFF0000u));
  }
  red[t] = c; __syncthreads();
  for (int s = 128; s > 0; s >>= 1){ if (t < s) red[t] += red[t+s]; __syncthreads(); }
  if (t == 0) *flag = (red[0] >= 1229) ? 1 : 0;
}

__global__ void starts_kernel(const int* __restrict__ batch, int* __restrict__ starts){
  int b = threadIdx.x;
  if (b < BB){
    int lo = 0, hi = NTOT;
    while (lo < hi){ int mid = (lo + hi) >> 1; if (batch[mid] < b) lo = mid + 1; else hi = mid; }
    starts[b] = lo;
  }
}

// ---------------- fused conversion of all 15 float tensors (1 launch) ----------------
struct ConvSeg { const void* src; void* dst; int n; int tobf; };
struct ConvArgs { ConvSeg s[15]; };

__global__ __launch_bounds__(256) void convall_kernel(ConvArgs a, const int* __restrict__ flag){
  const int isb = *flag;
  const int blk = blockIdx.x;
  int seg = -1, base = 0, lb = 0;
  #pragma unroll
  for (int i = 0; i < 15; ++i){
    int nb = (a.s[i].n + 1023) >> 10;
    if (seg < 0){
      if (blk < base + nb){ seg = i; lb = blk - base; }
      base += nb;
    }
  }
  const ConvSeg sg = a.s[seg];
  const int idx = lb*1024 + threadIdx.x*4;
  if (idx >= sg.n) return;
  if (sg.tobf){
    u16* dst = (u16*)sg.dst + idx;
    if (isb){
      *(uint2*)dst = *(const uint2*)((const u16*)sg.src + idx);
    } else {
      const float* s4 = (const float*)sg.src + idx;
      dst[0] = f2bf(s4[0]); dst[1] = f2bf(s4[1]);
      dst[2] = f2bf(s4[2]); dst[3] = f2bf(s4[3]);
    }
  } else {
    float* dst = (float*)sg.dst + idx;
    if (isb){
      const u16* s4 = (const u16*)sg.src + idx;
      dst[0] = bf2f(s4[0]); dst[1] = bf2f(s4[1]);
      dst[2] = bf2f(s4[2]); dst[3] = bf2f(s4[3]);
    } else {
      *(float4*)dst = *(const float4*)((const float*)sg.src + idx);
    }
  }
}

// ---------------- legacy small GEMM (input projection only) ----------------
__global__ __launch_bounds__(256) void gemm_bf16(
    const u16* __restrict__ A, int lda,
    const u16* __restrict__ W, int ldw,
    const float* __restrict__ bias,
    float* __restrict__ Cf, u16* __restrict__ Cb,
    int N, int K, int flags)
{
  __shared__ __align__(16) u16 At[64][32];
  __shared__ __align__(16) u16 Wt[64][32];
  const int t = threadIdx.x;
  const int m0 = blockIdx.x * 64, n0 = blockIdx.y * 64;
  const int wave = t >> 6, lane = t & 63;
  const int quad = lane >> 4, l16 = lane & 15;
  const int lr = t >> 2, lc = (t & 3) * 8;

  f32x4 acc[4];
  #pragma unroll
  for (int i = 0; i < 4; ++i){ acc[i][0]=0.f; acc[i][1]=0.f; acc[i][2]=0.f; acc[i][3]=0.f; }

  const u16* Arow = A + (size_t)(m0 + lr) * lda + lc;
  const u16* Wrow = W + (size_t)(n0 + lr) * ldw + lc;

  for (int k0 = 0; k0 < K; k0 += 32){
    uint4 av = *(const uint4*)(Arow + k0);
    uint4 wv = *(const uint4*)(Wrow + k0);
    __syncthreads();
    *(uint4*)&At[lr][lc] = av;
    *(uint4*)&Wt[lr][lc] = wv;
    __syncthreads();
    bf16x8 af = *(const bf16x8*)&At[wave*16 + l16][quad*8];
    #pragma unroll
    for (int nt = 0; nt < 4; ++nt){
      bf16x8 wf = *(const bf16x8*)&Wt[nt*16 + l16][quad*8];
      acc[nt] = __builtin_amdgcn_mfma_f32_16x16x32_bf16(af, wf, acc[nt], 0, 0, 0);
    }
  }
  const int row = m0 + wave*16 + quad*4;
  #pragma unroll
  for (int nt = 0; nt < 4; ++nt){
    const int col = n0 + nt*16 + l16;
    const float bv = bias ? bias[col] : 0.f;
    #pragma unroll
    for (int r = 0; r < 4; ++r){
      size_t idx = (size_t)(row + r) * N + col;
      float v = acc[nt][r] + bv;
      if (flags & 1) v = fmaxf(v, 0.f);
      if (Cf) Cf[idx] = v;
      if (Cb) Cb[idx] = f2bf(v);
    }
  }
}

// ---------------- scatter projected nodes into padded layout + mask ----------------
__global__ __launch_bounds__(128) void scatter_kernel(
    const float* __restrict__ hlin, const int* __restrict__ batch,
    const int* __restrict__ starts, float* __restrict__ cur,
    u16* __restrict__ curb, float* __restrict__ mask)
{
  int i = blockIdx.x, t = threadIdx.x;
  int g = batch[i];
  int p = i - starts[g];
  float v = hlin[(size_t)i*DD + t];
  float s = v;
  #pragma unroll
  for (int off = 32; off; off >>= 1) s += __shfl_xor(s, off);
  __shared__ float sh[2];
  if ((t & 63) == 0) sh[t >> 6] = s;
  __syncthreads();
  float rowsum = sh[0] + sh[1];
  if ((unsigned)p < (unsigned)NPER && (unsigned)g < (unsigned)BB){
    size_t j = (size_t)g*NPER + p;
    cur[j*DD + t]  = v;
    curb[j*DD + t] = f2bf(v);
    if (t == 0) mask[j] = (rowsum != 0.f) ? 1.f : 0.f;
  }
}

// ---------------- MFMA flash attention v2 ----------------
__global__ __launch_bounds__(256) void fattn_kernel(
    const u16* __restrict__ qkvb,   // [NTOT][384]
    const u16* __restrict__ vt,     // [B*H*HD][NPER]
    u16* __restrict__ attnob)       // [NTOT][128]
{
  __shared__ __align__(16) u16 Klds[2][2048];      // [c(4)][r(64)][8]
  __shared__ __align__(16) u16 Vl[2][2048];        // [cv(8)][d(32)][8]
  __shared__ __align__(16) u16 Pl[4][16*72];       // per-wave P [q][s], pitch 72

  const int t = threadIdx.x;
  const int wave = t >> 6, lane = t & 63;
  const int quad = lane >> 4, l16 = lane & 15;
  const int q0 = blockIdx.x * 64;
  const int h = blockIdx.y, b = blockIdx.z;
  const size_t qkvbase = (size_t)b * NPER * 384;
  const u16* Kg = qkvb + qkvbase + 128 + h*HD;
  const u16* Vg = vt + (size_t)((b*HH + h)*HD) * NPER;

  bf16x8 qf;
  {
    const u16* qp = qkvb + qkvbase + (size_t)(q0 + wave*16 + l16)*384 + h*HD + quad*8;
    uint4 qv = *(const uint4*)qp;
    u16 raw[8]; __builtin_memcpy(raw, &qv, 16);
    #pragma unroll
    for (int j = 0; j < 8; ++j) qf[j] = (short)f2bf(bf2f(raw[j]) * QKSCALE);
  }

  const int vcv = wave*2 + (lane >> 5), vd = lane & 31;
  auto stage = [&](int buf, int kt){
    __builtin_amdgcn_global_load_lds(
        AS_GLOBAL(Kg + (size_t)(kt*64 + lane)*384 + wave*8),
        AS_LDS(&Klds[buf][wave*64*8]), 16, 0, 0);
    __builtin_amdgcn_global_load_lds(
        AS_GLOBAL(Vg + (size_t)vd*NPER + kt*64 + vcv*8),
        AS_LDS(&Vl[buf][wave*64*8]), 16, 0, 0);
  };

  float lsum = 0.f;
  f32x4 o0 = {0.f,0.f,0.f,0.f}, o1 = {0.f,0.f,0.f,0.f};
  u16* Pw = &Pl[wave][0];

  stage(0, 0);
  asm volatile("s_waitcnt vmcnt(0)" ::: "memory");
  __syncthreads();

  for (int kt = 0; kt < 16; ++kt){
    const int buf = kt & 1;
    if (kt + 1 < 16) stage(buf ^ 1, kt + 1);

    f32x4 sfr[4];
    #pragma unroll
    for (int nt = 0; nt < 4; ++nt){
      bf16x8 kf = *(const bf16x8*)&Klds[buf][(quad*64 + nt*16 + l16)*8];
      f32x4 z = {0.f,0.f,0.f,0.f};
      sfr[nt] = __builtin_amdgcn_mfma_f32_16x16x32_bf16(kf, qf, z, 0, 0, 0);
    }

    float ps = 0.f;
    #pragma unroll
    for (int nt = 0; nt < 4; ++nt){
      float e0 = __expf(sfr[nt][0]), e1 = __expf(sfr[nt][1]);
      float e2 = __expf(sfr[nt][2]), e3 = __expf(sfr[nt][3]);
      ps += (e0 + e1) + (e2 + e3);
      uint2 w;
      w.x = (unsigned)f2bf(e0) | ((unsigned)f2bf(e1) << 16);
      w.y = (unsigned)f2bf(e2) | ((unsigned)f2bf(e3) << 16);
      *(uint2*)&Pw[l16*72 + nt*16 + quad*4] = w;
    }
    ps += __shfl_xor(ps, 16);
    ps += __shfl_xor(ps, 32);
    lsum += ps;
    asm volatile("s_waitcnt lgkmcnt(0)" ::: "memory");

    #pragma unroll
    for (int kk = 0; kk < 2; ++kk){
      bf16x8 pf = *(const bf16x8*)&Pw[l16*72 + kk*32 + quad*8];
      bf16x8 v0 = *(const bf16x8*)&Vl[buf][((kk*4 + quad)*32 + l16)*8];
      bf16x8 v1 = *(const bf16x8*)&Vl[buf][((kk*4 + quad)*32 + 16 + l16)*8];
      o0 = __builtin_amdgcn_mfma_f32_16x16x32_bf16(pf, v0, o0, 0, 0, 0);
      o1 = __builtin_amdgcn_mfma_f32_16x16x32_bf16(pf, v1, o1, 0, 0, 0);
    }

    if (kt + 1 < 16){
      asm volatile("s_waitcnt vmcnt(0)" ::: "memory");
      __syncthreads();
    }
  }

  #pragma unroll
  for (int r = 0; r < 4; ++r){
    float inv = 1.f / __shfl(lsum, quad*4 + r);
    int row = q0 + wave*16 + quad*4 + r;
    size_t base = (size_t)(b*NPER + row)*DD + h*HD;
    attnob[base + l16]      = f2bf(o0[r] * inv);
    attnob[base + 16 + l16] = f2bf(o1[r] * inv);
  }
}

// ---------------- LN epilogue (wave owns 16 rows): out = LN(resid + O + bias) ----------------
__device__ __forceinline__ void epilogue_ln64(
    const f32x4 O[8], int m0, int wave, int quad, int l16,
    const float* __restrict__ bias, const float* __restrict__ g,
    const float* __restrict__ beta, float* __restrict__ cur,
    u16* __restrict__ curb)
{
  #pragma unroll
  for (int rr = 0; rr < 4; ++rr){
    int row = m0 + wave*16 + quad*4 + rr;
    float vs[8], sum = 0.f;
    #pragma unroll
    for (int nt = 0; nt < 8; ++nt){
      int col = nt*16 + l16;
      float v = O[nt][rr] + bias[col] + cur[(size_t)row*DD + col];
      vs[nt] = v; sum += v;
    }
    sum += __shfl_xor(sum, 1); sum += __shfl_xor(sum, 2);
    sum += __shfl_xor(sum, 4); sum += __shfl_xor(sum, 8);
    float mean = sum * (1.f/DD);
    float sq = 0.f;
    #pragma unroll
    for (int nt = 0; nt < 8; ++nt){ float d = vs[nt] - mean; sq += d*d; }
    sq += __shfl_xor(sq, 1); sq += __shfl_xor(sq, 2);
    sq += __shfl_xor(sq, 4); sq += __shfl_xor(sq, 8);
    float rs = rsqrtf(sq * (1.f/DD) + 1e-5f);
    #pragma unroll
    for (int nt = 0; nt < 8; ++nt){
      int col = nt*16 + l16;
      float o = (vs[nt] - mean)*rs*g[col] + beta[col];
      cur[(size_t)row*DD + col]  = o;
      curb[(size_t)row*DD + col] = f2bf(o);
    }
  }
}

// ---------------- 64-row-block GEMM, W (128x128 slice) in LDS, A-frags in regs ----------------
__global__ __launch_bounds__(256) void wgemm_kernel(
    const u16* __restrict__ A,        // [M][128] bf16
    const u16* __restrict__ Wbase,    // [gridDim.y*128][128] bf16
    const float* __restrict__ biasb,  // [gridDim.y*128]
    int mode,
    u16* __restrict__ outb, int opitch,
    u16* __restrict__ vtout,
    float* __restrict__ cur, u16* __restrict__ curb,
    const float* __restrict__ g, const float* __restrict__ beta)
{
  __shared__ __align__(16) u16 Wl[16384];          // 128x128, XOR-swizzled chunks
  const int t = threadIdx.x, wave = t >> 6, lane = t & 63;
  const int quad = lane >> 4, l16 = lane & 15;
  const int m0 = blockIdx.x * 64, nb = blockIdx.y;
  const u16* Wsl = Wbase + (size_t)nb * 16384;
  const float* bias = biasb + nb * 128;

  #pragma unroll
  for (int j = 0; j < 8; ++j){
    int s = t + 256*j;
    int r = s >> 4, cx = (s & 15) ^ (r & 15);
    *(uint4*)&Wl[s*8] = *(const uint4*)(Wsl + (size_t)r*128 + cx*8);
  }
  bf16x8 af[4];
  #pragma unroll
  for (int kk = 0; kk < 4; ++kk)
    af[kk] = *(const bf16x8*)(A + (size_t)(m0 + wave*16 + l16)*128 + kk*32 + quad*8);
  __syncthreads();

  f32x4 O[8];
  #pragma unroll
  for (int nt = 0; nt < 8; ++nt){ O[nt][0]=0.f; O[nt][1]=0.f; O[nt][2]=0.f; O[nt][3]=0.f; }

  #pragma unroll
  for (int nt = 0; nt < 8; ++nt){
    int row = nt*16 + l16;
    bf16x8 wf[4];
    #pragma unroll
    for (int kk = 0; kk < 4; ++kk)
      wf[kk] = *(const bf16x8*)&Wl[(row*16 + ((kk*4 + quad) ^ l16))*8];
    #pragma unroll
    for (int kk = 0; kk < 4; ++kk)
      O[nt] = __builtin_amdgcn_mfma_f32_16x16x32_bf16(af[kk], wf[kk], O[nt], 0, 0, 0);
  }

  if (mode == 0){
    if (nb == 2 && vtout){
      int rowb = m0 + wave*16 + quad*4;
      int bg = rowb >> 10, s = rowb & 1023;
      #pragma unroll
      for (int nt = 0; nt < 8; ++nt){
        int col = nt*16 + l16;
        int hh = col >> 5, d = col & 31;
        float v0 = O[nt][0] + bias[col], v1 = O[nt][1] + bias[col];
        float v2 = O[nt][2] + bias[col], v3 = O[nt][3] + bias[col];
        uint2 w;
        w.x = (unsigned)f2bf(v0) | ((unsigned)f2bf(v1) << 16);
        w.y = (unsigned)f2bf(v2) | ((unsigned)f2bf(v3) << 16);
        *(uint2*)(vtout + (size_t)((bg*HH + hh)*HD + d)*NPER + s) = w;
      }
    } else {
      #pragma unroll
      for (int rr = 0; rr < 4; ++rr){
        int row = m0 + wave*16 + quad*4 + rr;
        #pragma unroll
        for (int nt = 0; nt < 8; ++nt){
          int col = nt*16 + l16;
          outb[(size_t)row*opitch + nb*128 + col] = f2bf(O[nt][rr] + bias[col]);
        }
      }
    }
  } else {
    epilogue_ln64(O, m0, wave, quad, l16, bias, g, beta, cur, curb);
  }
}

// ---------------- fused FFN v5: dff-split partial-K + register-shuffle P ----------------
// 512 blocks (2/CU, 8 waves/CU). Wave (ag, d): owns acts [m0+ag*32, +32) jointly
// with its d-partner; computes ONLY dff-half d of every 64-dff chunk, accumulating
// partial-K O[32 acts][128 cols]; halves summed in epilogue via one LDS exchange.
// Phase1 C (col=act, rows=dff-regs) is converted to phase2's A-layout by a 4x
// shfl_xor(.,32) h-half exchange -- ZERO P LDS, ONE barrier/chunk, no pair coupling.
// (All 32x32 fragment layouts HW-verified by R9's passing run.)
__global__ __launch_bounds__(256, 2) void ffn_kernel(
    const u16* __restrict__ Ag,       // CURB [M][128]
    const u16* __restrict__ W1g,      // [2048][128]
    const u16* __restrict__ W2g,      // [128][2048]
    const float* __restrict__ b1,
    const float* __restrict__ b2,
    const float* __restrict__ g, const float* __restrict__ beta,
    float* __restrict__ cur, u16* __restrict__ curb)
{
  __shared__ __align__(16) u16 W1l[2][8192];       // [64 dff][128 k], XOR16, x2 buf
  __shared__ __align__(16) u16 W2l[2][8192];       // [128 col][64 dff], XOR8, x2 buf

  const int t = threadIdx.x, wave = t >> 6, lane = t & 63;
  const int ag = wave >> 1, d = wave & 1;
  const int a32 = lane & 31, h = lane >> 5;
  const int m0 = blockIdx.x * 64;

  auto stage = [&](int buf, int dffc){
    #pragma unroll
    for (int i = 0; i < 4; ++i){
      const int s0 = wave*256 + i*64;
      const int s  = s0 + lane;
      { int r = s >> 4, cx = (s & 15) ^ (r & 15);
        __builtin_amdgcn_global_load_lds(
            AS_GLOBAL(W1g + (size_t)(dffc + r)*128 + cx*8),
            AS_LDS(&W1l[buf][s0*8]), 16, 0, 0); }
      { int col = s >> 3, c8 = (s & 7) ^ (col & 7);
        __builtin_amdgcn_global_load_lds(
            AS_GLOBAL(W2g + (size_t)col*DFF + dffc + c8*8),
            AS_LDS(&W2l[buf][s0*8]), 16, 0, 0); }
    }
  };

  // act B-frags (K=128): af[kk] covers k = kk*16 + h*8 .. +7
  bf16x8 af[8];
  #pragma unroll
  for (int kk = 0; kk < 8; ++kk)
    af[kk] = *(const bf16x8*)(Ag + (size_t)(m0 + ag*32 + a32)*128 + kk*16 + h*8);

  f32x16 O[4];
  #pragma unroll
  for (int nt = 0; nt < 4; ++nt)
    #pragma unroll
    for (int j = 0; j < 16; ++j) O[nt][j] = 0.f;

  stage(0, 0);
  asm volatile("s_waitcnt vmcnt(0)" ::: "memory");
  __syncthreads();

  const int w1r = d*32 + a32;                      // this wave's dff rows in chunk
  for (int c = 0; c < 32; ++c){
    const int buf = c & 1;
    if (c + 1 < 32) stage(buf ^ 1, (c + 1)*64);

    // ---- phase 1: C[dff32][act32] = W1(d-half) @ A^T, 2 chains, K=128 ----
    f32x16 s0v, s1v;
    #pragma unroll
    for (int j = 0; j < 16; ++j){ s0v[j] = 0.f; s1v[j] = 0.f; }
    #pragma unroll
    for (int kk = 0; kk < 8; kk += 2){
      bf16x8 wa = *(const bf16x8*)&W1l[buf][(w1r*16 + (((kk  )*2 + h) ^ (w1r & 15)))*8];
      bf16x8 wb = *(const bf16x8*)&W1l[buf][(w1r*16 + (((kk+1)*2 + h) ^ (w1r & 15)))*8];
      s0v = __builtin_amdgcn_mfma_f32_32x32x16_bf16(wa, af[kk],   s0v, 0, 0, 0);
      s1v = __builtin_amdgcn_mfma_f32_32x32x16_bf16(wb, af[kk+1], s1v, 0, 0, 0);
    }
    // bias + relu + pack to bf16 pairs: group gi holds dff-local gi*8 + 4h + 0..3
    unsigned pk[8];
    #pragma unroll
    for (int gi = 0; gi < 4; ++gi){
      f32x4 bv = *(const f32x4*)&b1[c*64 + d*32 + gi*8 + 4*h];
      float v0 = fmaxf(s0v[gi*4+0] + s1v[gi*4+0] + bv[0], 0.f);
      float v1 = fmaxf(s0v[gi*4+1] + s1v[gi*4+1] + bv[1], 0.f);
      float v2 = fmaxf(s0v[gi*4+2] + s1v[gi*4+2] + bv[2], 0.f);
      float v3 = fmaxf(s0v[gi*4+3] + s1v[gi*4+3] + bv[3], 0.f);
      pk[gi*2]   = (unsigned)f2bf(v0) | ((unsigned)f2bf(v1) << 16);
      pk[gi*2+1] = (unsigned)f2bf(v2) | ((unsigned)f2bf(v3) << 16);
    }

    // ---- phase 2: O += P @ W2c^T (K=32, this dff-half); A-frag via shfl ----
    #pragma unroll
    for (int kk = 0; kk < 2; ++kk){
      const int gown = 2*kk + h, gsend = 2*kk + 1 - h;
      unsigned own0 = pk[gown*2],  own1 = pk[gown*2 + 1];
      unsigned rc0 = (unsigned)__shfl_xor((int)pk[gsend*2],     32);
      unsigned rc1 = (unsigned)__shfl_xor((int)pk[gsend*2 + 1], 32);
      union { unsigned u[4]; bf16x8 v; } fr;
      fr.u[0] = h ? rc0  : own0;
      fr.u[1] = h ? rc1  : own1;
      fr.u[2] = h ? own0 : rc0;
      fr.u[3] = h ? own1 : rc1;
      #pragma unroll
      for (int nt = 0; nt < 4; ++nt){
        int col = nt*32 + a32;
        bf16x8 wf = *(const bf16x8*)&W2l[buf][(col*8 + ((d*4 + kk*2 + h) ^ (col & 7)))*8];
        O[nt] = __builtin_amdgcn_mfma_f32_32x32x16_bf16(fr.v, wf, O[nt], 0, 0, 0);
      }
    }

    if (c + 1 < 32){
      asm volatile("s_waitcnt vmcnt(0) lgkmcnt(0)\ns_barrier" ::: "memory");
    }
  }

  // ---- epilogue: sum d-halves via LDS, then residual + LN2 (d==0 waves) ----
  __syncthreads();
  float* scratch = (float*)&W1l[0][0];             // 32 KB: [2 groups][32 acts][128]
  if (d == 1){
    #pragma unroll
    for (int reg = 0; reg < 16; ++reg){
      int actl = (reg & 3) + 8*(reg >> 2) + 4*h;
      #pragma unroll
      for (int nt = 0; nt < 4; ++nt)
        scratch[ag*4096 + actl*128 + nt*32 + a32] = O[nt][reg];
    }
  }
  __syncthreads();
  if (d == 0){
    #pragma unroll
    for (int reg = 0; reg < 16; ++reg){
      int actl = (reg & 3) + 8*(reg >> 2) + 4*h;
      int row = m0 + ag*32 + actl;
      float vs[4], sum = 0.f;
      #pragma unroll
      for (int nt = 0; nt < 4; ++nt){
        int col = nt*32 + a32;
        float v = O[nt][reg] + scratch[ag*4096 + actl*128 + col]
                + b2[col] + cur[(size_t)row*DD + col];
        vs[nt] = v; sum += v;
      }
      sum += __shfl_xor(sum, 1); sum += __shfl_xor(sum, 2);
      sum += __shfl_xor(sum, 4); sum += __shfl_xor(sum, 8); sum += __shfl_xor(sum, 16);
      float mean = sum * (1.f/DD);
      float sq = 0.f;
      #pragma unroll
      for (int nt = 0; nt < 4; ++nt){ float dv = vs[nt] - mean; sq += dv*dv; }
      sq += __shfl_xor(sq, 1); sq += __shfl_xor(sq, 2);
      sq += __shfl_xor(sq, 4); sq += __shfl_xor(sq, 8); sq += __shfl_xor(sq, 16);
      float rs = rsqrtf(sq * (1.f/DD) + 1e-5f);
      #pragma unroll
      for (int nt = 0; nt < 4; ++nt){
        int col = nt*32 + a32;
        float o = (vs[nt] - mean)*rs*g[col] + beta[col];
        cur[(size_t)row*DD + col]  = o;
        curb[(size_t)row*DD + col] = f2bf(o);
      }
    }
  }
}

// ---------------- final masked mean, two-stage ----------------
__global__ __launch_bounds__(128) void reduce1_kernel(
    const float* __restrict__ cur, const float* __restrict__ mask,
    float* __restrict__ partial, float* __restrict__ cnt)
{
  int b = blockIdx.x, c = blockIdx.y, t = threadIdx.x;
  float acc = 0.f, cn = 0.f;
  for (int s = c*128; s < c*128 + 128; ++s){
    float mk = mask[b*NPER + s];
    acc += cur[(size_t)(b*NPER + s)*DD + t] * mk;
    cn += mk;
  }
  partial[(size_t)(b*8 + c)*DD + t] = acc;
  if (t == 0) cnt[b*8 + c] = cn;
}
__global__ __launch_bounds__(128) void reduce2_kernel(
    const float* __restrict__ partial, const float* __restrict__ cnt,
    const int* __restrict__ flag, void* __restrict__ out)
{
  int b = blockIdx.x, t = threadIdx.x;
  float acc = 0.f, cn = 0.f;
  #pragma unroll
  for (int c = 0; c < 8; ++c){
    acc += partial[(size_t)(b*8 + c)*DD + t];
    cn  += cnt[b*8 + c];
  }
  float val = acc / cn;
  if (*flag) ((u16*)out)[b*DD + t] = f2bf(val);
  else       ((float*)out)[b*DD + t] = val;
}

// ---------------- host ----------------
extern "C" void kernel_launch(void* const* d_in, const int* in_sizes, int n_in,
                              void* d_out, int out_size, void* d_ws, size_t ws_size,
                              hipStream_t stream)
{
  (void)in_sizes; (void)n_in; (void)out_size; (void)ws_size;
  char* ws = (char*)d_ws;
  int*   flag   = (int*)(ws + OFF_FLAG);
  int*   starts = (int*)(ws + OFF_STARTS);
  float* BIN  = (float*)(ws + OFF_BIN);
  float* BQKV = (float*)(ws + OFF_BQKV);
  float* BO   = (float*)(ws + OFF_BO);
  float* B1   = (float*)(ws + OFF_B1);
  float* B2   = (float*)(ws + OFF_B2);
  float* LN1G = (float*)(ws + OFF_LN1G);
  float* LN1B = (float*)(ws + OFF_LN1B);
  float* LN2G = (float*)(ws + OFF_LN2G);
  float* LN2B = (float*)(ws + OFF_LN2B);
  u16* XB    = (u16*)(ws + OFF_XB);
  u16* WINB  = (u16*)(ws + OFF_WINB);
  u16* WQKVB = (u16*)(ws + OFF_WQKVB);
  u16* WOB   = (u16*)(ws + OFF_WOB);
  u16* W1B   = (u16*)(ws + OFF_W1B);
  u16* W2B   = (u16*)(ws + OFF_W2B);
  float* CUR = (float*)(ws + OFF_CUR);
  float* TMP = (float*)(ws + OFF_TMP);
  u16* CURB  = (u16*)(ws + OFF_CURB);
  u16* QKVB  = (u16*)(ws + OFF_QKVB);
  u16* ATTNOB= (u16*)(ws + OFF_ATTNOB);
  float* MASK= (float*)(ws + OFF_MASK);
  u16* VT    = (u16*)(ws + OFF_VT);
  float* RED = (float*)(ws + OFF_RED);
  float* CNT = (float*)(ws + OFF_CNT);

  detect_kernel<<<1, 256, 0, stream>>>((const unsigned*)d_in[0], flag);
  starts_kernel<<<1, 64, 0, stream>>>((const int*)d_in[1], starts);

  ConvArgs ca;
  ca.s[0]  = { d_in[0],  XB,    NTOT*INDIM, 1 };
  ca.s[1]  = { d_in[2],  WINB,  DD*INDIM,   1 };
  ca.s[2]  = { d_in[4],  WQKVB, LL*3*DD*DD, 1 };
  ca.s[3]  = { d_in[6],  WOB,   LL*DD*DD,   1 };
  ca.s[4]  = { d_in[8],  W1B,   LL*DFF*DD,  1 };
  ca.s[5]  = { d_in[10], W2B,   LL*DD*DFF,  1 };
  ca.s[6]  = { d_in[3],  BIN,   DD,         0 };
  ca.s[7]  = { d_in[5],  BQKV,  LL*3*DD,    0 };
  ca.s[8]  = { d_in[7],  BO,    LL*DD,      0 };
  ca.s[9]  = { d_in[9],  B1,    LL*DFF,     0 };
  ca.s[10] = { d_in[11], B2,    LL*DD,      0 };
  ca.s[11] = { d_in[12], LN1G,  LL*DD,      0 };
  ca.s[12] = { d_in[13], LN1B,  LL*DD,      0 };
  ca.s[13] = { d_in[14], LN2G,  LL*DD,      0 };
  ca.s[14] = { d_in[15], LN2B,  LL*DD,      0 };
  int nblk = 0;
  for (int i = 0; i < 15; ++i) nblk += (ca.s[i].n + 1023) >> 10;
  convall_kernel<<<nblk, 256, 0, stream>>>(ca, flag);

  gemm_bf16<<<dim3(NTOT/64, DD/64), 256, 0, stream>>>(
      XB, INDIM, WINB, INDIM, BIN, TMP, nullptr, DD, INDIM, 0);
  scatter_kernel<<<NTOT, 128, 0, stream>>>(TMP, (const int*)d_in[1], starts, CUR, CURB, MASK);

  for (int l = 0; l < LL; ++l){
    wgemm_kernel<<<dim3(NTOT/64, 3), 256, 0, stream>>>(
        CURB, WQKVB + (size_t)l*3*DD*DD, BQKV + l*3*DD, 0,
        QKVB, 384, VT, nullptr, nullptr, nullptr, nullptr);
    fattn_kernel<<<dim3(NPER/64, HH, BB), 256, 0, stream>>>(QKVB, VT, ATTNOB);
    wgemm_kernel<<<dim3(NTOT/64, 1), 256, 0, stream>>>(
        ATTNOB, WOB + (size_t)l*DD*DD, BO + l*DD, 1,
        nullptr, 0, nullptr, CUR, CURB, LN1G + l*DD, LN1B + l*DD);
    ffn_kernel<<<dim3(NTOT/64), 256, 0, stream>>>(
        CURB, W1B + (size_t)l*DFF*DD, W2B + (size_t)l*DD*DFF,
        B1 + l*DFF, B2 + l*DD, LN2G + l*DD, LN2B + l*DD, CUR, CURB);
  }

  reduce1_kernel<<<dim3(BB, 8), 128, 0, stream>>>(CUR, MASK, RED, CNT);
  reduce2_kernel<<<BB, 128, 0, stream>>>(RED, CNT, flag, d_out);
}

// Round 11
// 507.805 us; speedup vs baseline: 1.1196x; 1.1196x over previous
//
#include <hip/hip_runtime.h>
#include <hip/hip_bf16.h>
#include <stdint.h>

// ---------------- static problem sizes ----------------
#define BB    32
#define NPER  1024
#define NTOT  32768
#define DD    128
#define HH    4
#define HD    32
#define LL    3
#define DFF   2048
#define INDIM 64
#define QKSCALE 0.17677669529663687f

typedef unsigned short u16;
typedef short bf16x8 __attribute__((ext_vector_type(8)));   // 8 bf16 (4 VGPRs)
typedef float f32x4 __attribute__((ext_vector_type(4)));

// address-space casts for global_load_lds (direct global->LDS DMA)
#define AS_GLOBAL(p) ((const __attribute__((address_space(1))) void*)(p))
#define AS_LDS(p)    ((__attribute__((address_space(3))) void*)(p))

__device__ __forceinline__ float bf2f(u16 v){
  unsigned u = ((unsigned)v) << 16; float f; __builtin_memcpy(&f, &u, 4); return f;
}
__device__ __forceinline__ u16 f2bf(float f){
  unsigned u; __builtin_memcpy(&u, &f, 4);
  unsigned lsb = (u >> 16) & 1u;
  u += 0x7fffu + lsb;              // round-to-nearest-even
  return (u16)(u >> 16);
}

// ---------------- workspace layout (bytes) ----------------
constexpr size_t OFF_FLAG   = 0;
constexpr size_t OFF_STARTS = 256;
constexpr size_t OFF_BIN    = 1024;
constexpr size_t OFF_BQKV   = OFF_BIN   + 128*4;
constexpr size_t OFF_BO     = OFF_BQKV  + 1152*4;
constexpr size_t OFF_B1     = OFF_BO    + 384*4;
constexpr size_t OFF_B2     = OFF_B1    + 6144*4;
constexpr size_t OFF_LN1G   = OFF_B2    + 384*4;
constexpr size_t OFF_LN1B   = OFF_LN1G  + 384*4;
constexpr size_t OFF_LN2G   = OFF_LN1B  + 384*4;
constexpr size_t OFF_LN2B   = OFF_LN2G  + 384*4;
constexpr size_t OFF_XB     = 40960;
constexpr size_t OFF_WINB   = OFF_XB    + (size_t)2097152*2;
constexpr size_t OFF_WQKVB  = OFF_WINB  + (size_t)8192*2;
constexpr size_t OFF_WOB    = OFF_WQKVB + (size_t)147456*2;
constexpr size_t OFF_W1B    = OFF_WOB   + (size_t)49152*2;
constexpr size_t OFF_W2B    = OFF_W1B   + (size_t)786432*2;
constexpr size_t OFF_CUR    = OFF_W2B   + (size_t)786432*2;
constexpr size_t OFF_TMP    = OFF_CUR   + (size_t)4194304*4;
constexpr size_t OFF_CURB   = OFF_TMP   + (size_t)4194304*4;
constexpr size_t OFF_QKVB   = OFF_CURB  + (size_t)4194304*2;
constexpr size_t OFF_ATTNOB = OFF_QKVB  + (size_t)12582912*2;
constexpr size_t OFF_ACTB   = OFF_ATTNOB+ (size_t)4194304*2;     // (unused now)
constexpr size_t OFF_MASK   = OFF_ACTB  + (size_t)16777216*2;
constexpr size_t OFF_VT     = OFF_MASK  + (size_t)NTOT*4;
constexpr size_t OFF_RED    = OFF_VT    + (size_t)4096*1024*2;
constexpr size_t OFF_CNT    = OFF_RED   + (size_t)32*8*128*4;

// ---------------- dtype detection ----------------
__device__ __forceinline__ int plaus(unsigned bits){
  if ((bits << 1) == 0u) return 1;
  unsigned e = (bits >> 23) & 0xFFu;
  return (e >= 100u && e <= 140u) ? 1 : 0;
}
__global__ void detect_kernel(const unsigned* __restrict__ x, int* __restrict__ flag){
  __shared__ int red[256];
  int t = threadIdx.x, c = 0;
  for (int i = t; i < 2048; i += 256){
    unsigned w = x[i];
    c += (plaus(w << 16) & plaus(w & 0xFFFF0000u));
  }
  red[t] = c; __syncthreads();
  for (int s = 128; s > 0; s >>= 1){ if (t < s) red[t] += red[t+s]; __syncthreads(); }
  if (t == 0) *flag = (red[0] >= 1229) ? 1 : 0;
}

__global__ void starts_kernel(const int* __restrict__ batch, int* __restrict__ starts){
  int b = threadIdx.x;
  if (b < BB){
    int lo = 0, hi = NTOT;
    while (lo < hi){ int mid = (lo + hi) >> 1; if (batch[mid] < b) lo = mid + 1; else hi = mid; }
    starts[b] = lo;
  }
}

// ---------------- fused conversion of all 15 float tensors (1 launch) ----------------
struct ConvSeg { const void* src; void* dst; int n; int tobf; };
struct ConvArgs { ConvSeg s[15]; };

__global__ __launch_bounds__(256) void convall_kernel(ConvArgs a, const int* __restrict__ flag){
  const int isb = *flag;
  const int blk = blockIdx.x;
  int seg = -1, base = 0, lb = 0;
  #pragma unroll
  for (int i = 0; i < 15; ++i){
    int nb = (a.s[i].n + 1023) >> 10;
    if (seg < 0){
      if (blk < base + nb){ seg = i; lb = blk - base; }
      base += nb;
    }
  }
  const ConvSeg sg = a.s[seg];
  const int idx = lb*1024 + threadIdx.x*4;
  if (idx >= sg.n) return;
  if (sg.tobf){
    u16* dst = (u16*)sg.dst + idx;
    if (isb){
      *(uint2*)dst = *(const uint2*)((const u16*)sg.src + idx);
    } else {
      const float* s4 = (const float*)sg.src + idx;
      dst[0] = f2bf(s4[0]); dst[1] = f2bf(s4[1]);
      dst[2] = f2bf(s4[2]); dst[3] = f2bf(s4[3]);
    }
  } else {
    float* dst = (float*)sg.dst + idx;
    if (isb){
      const u16* s4 = (const u16*)sg.src + idx;
      dst[0] = bf2f(s4[0]); dst[1] = bf2f(s4[1]);
      dst[2] = bf2f(s4[2]); dst[3] = bf2f(s4[3]);
    } else {
      *(float4*)dst = *(const float4*)((const float*)sg.src + idx);
    }
  }
}

// ---------------- legacy small GEMM (input projection only) ----------------
__global__ __launch_bounds__(256) void gemm_bf16(
    const u16* __restrict__ A, int lda,
    const u16* __restrict__ W, int ldw,
    const float* __restrict__ bias,
    float* __restrict__ Cf, u16* __restrict__ Cb,
    int N, int K, int flags)
{
  __shared__ __align__(16) u16 At[64][32];
  __shared__ __align__(16) u16 Wt[64][32];
  const int t = threadIdx.x;
  const int m0 = blockIdx.x * 64, n0 = blockIdx.y * 64;
  const int wave = t >> 6, lane = t & 63;
  const int quad = lane >> 4, l16 = lane & 15;
  const int lr = t >> 2, lc = (t & 3) * 8;

  f32x4 acc[4];
  #pragma unroll
  for (int i = 0; i < 4; ++i){ acc[i][0]=0.f; acc[i][1]=0.f; acc[i][2]=0.f; acc[i][3]=0.f; }

  const u16* Arow = A + (size_t)(m0 + lr) * lda + lc;
  const u16* Wrow = W + (size_t)(n0 + lr) * ldw + lc;

  for (int k0 = 0; k0 < K; k0 += 32){
    uint4 av = *(const uint4*)(Arow + k0);
    uint4 wv = *(const uint4*)(Wrow + k0);
    __syncthreads();
    *(uint4*)&At[lr][lc] = av;
    *(uint4*)&Wt[lr][lc] = wv;
    __syncthreads();
    bf16x8 af = *(const bf16x8*)&At[wave*16 + l16][quad*8];
    #pragma unroll
    for (int nt = 0; nt < 4; ++nt){
      bf16x8 wf = *(const bf16x8*)&Wt[nt*16 + l16][quad*8];
      acc[nt] = __builtin_amdgcn_mfma_f32_16x16x32_bf16(af, wf, acc[nt], 0, 0, 0);
    }
  }
  const int row = m0 + wave*16 + quad*4;
  #pragma unroll
  for (int nt = 0; nt < 4; ++nt){
    const int col = n0 + nt*16 + l16;
    const float bv = bias ? bias[col] : 0.f;
    #pragma unroll
    for (int r = 0; r < 4; ++r){
      size_t idx = (size_t)(row + r) * N + col;
      float v = acc[nt][r] + bv;
      if (flags & 1) v = fmaxf(v, 0.f);
      if (Cf) Cf[idx] = v;
      if (Cb) Cb[idx] = f2bf(v);
    }
  }
}

// ---------------- scatter projected nodes into padded layout + mask ----------------
__global__ __launch_bounds__(128) void scatter_kernel(
    const float* __restrict__ hlin, const int* __restrict__ batch,
    const int* __restrict__ starts, float* __restrict__ cur,
    u16* __restrict__ curb, float* __restrict__ mask)
{
  int i = blockIdx.x, t = threadIdx.x;
  int g = batch[i];
  int p = i - starts[g];
  float v = hlin[(size_t)i*DD + t];
  float s = v;
  #pragma unroll
  for (int off = 32; off; off >>= 1) s += __shfl_xor(s, off);
  __shared__ float sh[2];
  if ((t & 63) == 0) sh[t >> 6] = s;
  __syncthreads();
  float rowsum = sh[0] + sh[1];
  if ((unsigned)p < (unsigned)NPER && (unsigned)g < (unsigned)BB){
    size_t j = (size_t)g*NPER + p;
    cur[j*DD + t]  = v;
    curb[j*DD + t] = f2bf(v);
    if (t == 0) mask[j] = (rowsum != 0.f) ? 1.f : 0.f;
  }
}

// ---------------- MFMA flash attention v3: 32 q-rows per wave ----------------
// grid (NPER/128, H, B) = 1024 blocks, 4 blocks/CU, 16 waves/CU.
// K-frag and V-frag LDS reads are shared across the wave's 2 q-tiles:
// 20 LDS ops per 16 MFMA (v2: 14 per 8) -> halves K/V read duplication.
__global__ __launch_bounds__(256) void fattn_kernel(
    const u16* __restrict__ qkvb,   // [NTOT][384]
    const u16* __restrict__ vt,     // [B*H*HD][NPER]
    u16* __restrict__ attnob)       // [NTOT][128]
{
  __shared__ __align__(16) u16 Klds[2][2048];      // [c(4)][r(64)][8]
  __shared__ __align__(16) u16 Vl[2][2048];        // [cv(8)][d(32)][8]
  __shared__ __align__(16) u16 Pl[4][2][16*72];    // per-(wave,qt) P [q][s], pitch 72

  const int t = threadIdx.x;
  const int wave = t >> 6, lane = t & 63;
  const int quad = lane >> 4, l16 = lane & 15;
  const int q0 = blockIdx.x * 128;
  const int h = blockIdx.y, b = blockIdx.z;
  const size_t qkvbase = (size_t)b * NPER * 384;
  const u16* Kg = qkvb + qkvbase + 128 + h*HD;
  const u16* Vg = vt + (size_t)((b*HH + h)*HD) * NPER;

  // Q B-frags (scaled), one per q-tile
  bf16x8 qf[2];
  #pragma unroll
  for (int qt = 0; qt < 2; ++qt){
    const u16* qp = qkvb + qkvbase + (size_t)(q0 + wave*32 + qt*16 + l16)*384 + h*HD + quad*8;
    uint4 qv = *(const uint4*)qp;
    u16 raw[8]; __builtin_memcpy(raw, &qv, 16);
    #pragma unroll
    for (int j = 0; j < 8; ++j) qf[qt][j] = (short)f2bf(bf2f(raw[j]) * QKSCALE);
  }

  const int vcv = wave*2 + (lane >> 5), vd = lane & 31;
  auto stage = [&](int buf, int kt){
    __builtin_amdgcn_global_load_lds(
        AS_GLOBAL(Kg + (size_t)(kt*64 + lane)*384 + wave*8),
        AS_LDS(&Klds[buf][wave*64*8]), 16, 0, 0);
    __builtin_amdgcn_global_load_lds(
        AS_GLOBAL(Vg + (size_t)vd*NPER + kt*64 + vcv*8),
        AS_LDS(&Vl[buf][wave*64*8]), 16, 0, 0);
  };

  float lsum[2] = {0.f, 0.f};
  f32x4 o[2][2];
  #pragma unroll
  for (int qt = 0; qt < 2; ++qt)
    #pragma unroll
    for (int i = 0; i < 2; ++i){ o[qt][i][0]=0.f; o[qt][i][1]=0.f; o[qt][i][2]=0.f; o[qt][i][3]=0.f; }

  stage(0, 0);
  asm volatile("s_waitcnt vmcnt(0)" ::: "memory");
  __syncthreads();

  for (int kt = 0; kt < 16; ++kt){
    const int buf = kt & 1;
    if (kt + 1 < 16) stage(buf ^ 1, kt + 1);

    // S^T tiles, K-frag shared across both q-tiles
    f32x4 sfr[2][4];
    #pragma unroll
    for (int nt = 0; nt < 4; ++nt){
      bf16x8 kf = *(const bf16x8*)&Klds[buf][(quad*64 + nt*16 + l16)*8];
      f32x4 z = {0.f,0.f,0.f,0.f};
      sfr[0][nt] = __builtin_amdgcn_mfma_f32_16x16x32_bf16(kf, qf[0], z, 0, 0, 0);
      sfr[1][nt] = __builtin_amdgcn_mfma_f32_16x16x32_bf16(kf, qf[1], z, 0, 0, 0);
    }

    // exp -> packed bf16 P[q][s] (b64 writes), in-lane partial sums
    #pragma unroll
    for (int qt = 0; qt < 2; ++qt){
      float ps = 0.f;
      #pragma unroll
      for (int nt = 0; nt < 4; ++nt){
        float e0 = __expf(sfr[qt][nt][0]), e1 = __expf(sfr[qt][nt][1]);
        float e2 = __expf(sfr[qt][nt][2]), e3 = __expf(sfr[qt][nt][3]);
        ps += (e0 + e1) + (e2 + e3);
        uint2 w;
        w.x = (unsigned)f2bf(e0) | ((unsigned)f2bf(e1) << 16);
        w.y = (unsigned)f2bf(e2) | ((unsigned)f2bf(e3) << 16);
        *(uint2*)&Pl[wave][qt][l16*72 + nt*16 + quad*4] = w;
      }
      ps += __shfl_xor(ps, 16);
      ps += __shfl_xor(ps, 32);
      lsum[qt] += ps;
    }
    asm volatile("s_waitcnt lgkmcnt(0)" ::: "memory");   // P write -> A-frag read

    // O += P V : V-frags shared across both q-tiles
    #pragma unroll
    for (int kk = 0; kk < 2; ++kk){
      bf16x8 v0 = *(const bf16x8*)&Vl[buf][((kk*4 + quad)*32 + l16)*8];
      bf16x8 v1 = *(const bf16x8*)&Vl[buf][((kk*4 + quad)*32 + 16 + l16)*8];
      #pragma unroll
      for (int qt = 0; qt < 2; ++qt){
        bf16x8 pf = *(const bf16x8*)&Pl[wave][qt][l16*72 + kk*32 + quad*8];
        o[qt][0] = __builtin_amdgcn_mfma_f32_16x16x32_bf16(pf, v0, o[qt][0], 0, 0, 0);
        o[qt][1] = __builtin_amdgcn_mfma_f32_16x16x32_bf16(pf, v1, o[qt][1], 0, 0, 0);
      }
    }

    if (kt + 1 < 16){
      asm volatile("s_waitcnt vmcnt(0)" ::: "memory");
      __syncthreads();
    }
  }

  // epilogue: O rows q=quad*4+r, col d=l16; lsum lives at lane l16=q
  #pragma unroll
  for (int qt = 0; qt < 2; ++qt){
    #pragma unroll
    for (int r = 0; r < 4; ++r){
      float inv = 1.f / __shfl(lsum[qt], quad*4 + r);
      int row = q0 + wave*32 + qt*16 + quad*4 + r;
      size_t base = (size_t)(b*NPER + row)*DD + h*HD;
      attnob[base + l16]      = f2bf(o[qt][0][r] * inv);
      attnob[base + 16 + l16] = f2bf(o[qt][1][r] * inv);
    }
  }
}

// ---------------- LN epilogue (wave owns 16 rows): out = LN(resid + O + bias) ----------------
__device__ __forceinline__ void epilogue_ln64(
    const f32x4 O[8], int m0, int wave, int quad, int l16,
    const float* __restrict__ bias, const float* __restrict__ g,
    const float* __restrict__ beta, float* __restrict__ cur,
    u16* __restrict__ curb)
{
  #pragma unroll
  for (int rr = 0; rr < 4; ++rr){
    int row = m0 + wave*16 + quad*4 + rr;
    float vs[8], sum = 0.f;
    #pragma unroll
    for (int nt = 0; nt < 8; ++nt){
      int col = nt*16 + l16;
      float v = O[nt][rr] + bias[col] + cur[(size_t)row*DD + col];
      vs[nt] = v; sum += v;
    }
    sum += __shfl_xor(sum, 1); sum += __shfl_xor(sum, 2);
    sum += __shfl_xor(sum, 4); sum += __shfl_xor(sum, 8);
    float mean = sum * (1.f/DD);
    float sq = 0.f;
    #pragma unroll
    for (int nt = 0; nt < 8; ++nt){ float d = vs[nt] - mean; sq += d*d; }
    sq += __shfl_xor(sq, 1); sq += __shfl_xor(sq, 2);
    sq += __shfl_xor(sq, 4); sq += __shfl_xor(sq, 8);
    float rs = rsqrtf(sq * (1.f/DD) + 1e-5f);
    #pragma unroll
    for (int nt = 0; nt < 8; ++nt){
      int col = nt*16 + l16;
      float o = (vs[nt] - mean)*rs*g[col] + beta[col];
      cur[(size_t)row*DD + col]  = o;
      curb[(size_t)row*DD + col] = f2bf(o);
    }
  }
}

// ---------------- 64-row-block GEMM, W (128x128 slice) in LDS, A-frags in regs ----------------
__global__ __launch_bounds__(256) void wgemm_kernel(
    const u16* __restrict__ A,        // [M][128] bf16
    const u16* __restrict__ Wbase,    // [gridDim.y*128][128] bf16
    const float* __restrict__ biasb,  // [gridDim.y*128]
    int mode,
    u16* __restrict__ outb, int opitch,
    u16* __restrict__ vtout,
    float* __restrict__ cur, u16* __restrict__ curb,
    const float* __restrict__ g, const float* __restrict__ beta)
{
  __shared__ __align__(16) u16 Wl[16384];          // 128x128, XOR-swizzled chunks
  const int t = threadIdx.x, wave = t >> 6, lane = t & 63;
  const int quad = lane >> 4, l16 = lane & 15;
  const int m0 = blockIdx.x * 64, nb = blockIdx.y;
  const u16* Wsl = Wbase + (size_t)nb * 16384;
  const float* bias = biasb + nb * 128;

  #pragma unroll
  for (int j = 0; j < 8; ++j){
    int s = t + 256*j;
    int r = s >> 4, cx = (s & 15) ^ (r & 15);
    *(uint4*)&Wl[s*8] = *(const uint4*)(Wsl + (size_t)r*128 + cx*8);
  }
  bf16x8 af[4];
  #pragma unroll
  for (int kk = 0; kk < 4; ++kk)
    af[kk] = *(const bf16x8*)(A + (size_t)(m0 + wave*16 + l16)*128 + kk*32 + quad*8);
  __syncthreads();

  f32x4 O[8];
  #pragma unroll
  for (int nt = 0; nt < 8; ++nt){ O[nt][0]=0.f; O[nt][1]=0.f; O[nt][2]=0.f; O[nt][3]=0.f; }

  #pragma unroll
  for (int nt = 0; nt < 8; ++nt){
    int row = nt*16 + l16;
    bf16x8 wf[4];
    #pragma unroll
    for (int kk = 0; kk < 4; ++kk)
      wf[kk] = *(const bf16x8*)&Wl[(row*16 + ((kk*4 + quad) ^ l16))*8];
    #pragma unroll
    for (int kk = 0; kk < 4; ++kk)
      O[nt] = __builtin_amdgcn_mfma_f32_16x16x32_bf16(af[kk], wf[kk], O[nt], 0, 0, 0);
  }

  if (mode == 0){
    if (nb == 2 && vtout){
      int rowb = m0 + wave*16 + quad*4;
      int bg = rowb >> 10, s = rowb & 1023;
      #pragma unroll
      for (int nt = 0; nt < 8; ++nt){
        int col = nt*16 + l16;
        int hh = col >> 5, d = col & 31;
        float v0 = O[nt][0] + bias[col], v1 = O[nt][1] + bias[col];
        float v2 = O[nt][2] + bias[col], v3 = O[nt][3] + bias[col];
        uint2 w;
        w.x = (unsigned)f2bf(v0) | ((unsigned)f2bf(v1) << 16);
        w.y = (unsigned)f2bf(v2) | ((unsigned)f2bf(v3) << 16);
        *(uint2*)(vtout + (size_t)((bg*HH + hh)*HD + d)*NPER + s) = w;
      }
    } else {
      #pragma unroll
      for (int rr = 0; rr < 4; ++rr){
        int row = m0 + wave*16 + quad*4 + rr;
        #pragma unroll
        for (int nt = 0; nt < 8; ++nt){
          int col = nt*16 + l16;
          outb[(size_t)row*opitch + nb*128 + col] = f2bf(O[nt][rr] + bias[col]);
        }
      }
    }
  } else {
    epilogue_ln64(O, m0, wave, quad, l16, bias, g, beta, cur, curb);
  }
}

// ---------------- fused FFN v6: R7 structure + packed P writes ----------------
// 64-row blocks, 512 blocks (2/CU, 8 waves/CU), W double-buffered via DMA.
// Phase1 operand-swapped (mfma(wf, af)): C[dff=quad*4+r][act=l16] -> P written
// as 4 packed b64 stores/chunk (R7: 16 scalar b16). Phase2/epilogue = R7 exact.
__global__ __launch_bounds__(256, 2) void ffn_kernel(
    const u16* __restrict__ Ag,       // CURB [M][128]
    const u16* __restrict__ W1g,      // [2048][128]
    const u16* __restrict__ W2g,      // [128][2048]
    const float* __restrict__ b1,
    const float* __restrict__ b2,
    const float* __restrict__ g, const float* __restrict__ beta,
    float* __restrict__ cur, u16* __restrict__ curb)
{
  __shared__ __align__(16) u16 W1l[2][8192];       // 64x128 chunk, swizzled, x2 buf
  __shared__ __align__(16) u16 W2l[2][8192];       // 128x64 chunk, swizzled, x2 buf
  __shared__ __align__(16) u16 Pl[4][16*72];       // per-wave act, pitch 72

  const int t = threadIdx.x, wave = t >> 6, lane = t & 63;
  const int quad = lane >> 4, l16 = lane & 15;
  const int m0 = blockIdx.x * 64;
  u16* Pw = &Pl[wave][0];

  auto stage = [&](int buf, int dffc){
    #pragma unroll
    for (int i = 0; i < 4; ++i){
      const int s0 = wave*256 + i*64;
      const int s  = s0 + lane;
      { int r = s >> 4, cx = (s & 15) ^ (r & 15);
        __builtin_amdgcn_global_load_lds(
            AS_GLOBAL(W1g + (size_t)(dffc + r)*128 + cx*8),
            AS_LDS(&W1l[buf][s0*8]), 16, 0, 0); }
      { int r = s >> 3, cx = (s & 7) ^ (r & 7);
        __builtin_amdgcn_global_load_lds(
            AS_GLOBAL(W2g + (size_t)r*DFF + dffc + cx*8),
            AS_LDS(&W2l[buf][s0*8]), 16, 0, 0); }
    }
  };

  bf16x8 af[4];
  #pragma unroll
  for (int kk = 0; kk < 4; ++kk)
    af[kk] = *(const bf16x8*)(Ag + (size_t)(m0 + wave*16 + l16)*128 + kk*32 + quad*8);

  f32x4 O[8];
  #pragma unroll
  for (int nt = 0; nt < 8; ++nt){ O[nt][0]=0.f; O[nt][1]=0.f; O[nt][2]=0.f; O[nt][3]=0.f; }

  stage(0, 0);
  asm volatile("s_waitcnt vmcnt(0)" ::: "memory");
  __syncthreads();

  for (int c = 0; c < 32; ++c){
    const int buf = c & 1;
    if (c + 1 < 32) stage(buf ^ 1, (c + 1)*64);

    // phase 1 (operand-swapped): C[dff=nt*16+quad*4+r][act=l16]
    #pragma unroll
    for (int nt = 0; nt < 4; ++nt){
      int row = nt*16 + l16;                       // dff-local row for wf load
      bf16x8 wf[4];
      #pragma unroll
      for (int kk = 0; kk < 4; ++kk)
        wf[kk] = *(const bf16x8*)&W1l[buf][(row*16 + ((kk*4 + quad) ^ l16))*8];
      f32x4 b1v = *(const f32x4*)&b1[c*64 + nt*16 + quad*4];
      f32x4 s = {0.f,0.f,0.f,0.f};
      #pragma unroll
      for (int kk = 0; kk < 4; ++kk)
        s = __builtin_amdgcn_mfma_f32_16x16x32_bf16(wf[kk], af[kk], s, 0, 0, 0);
      float v0 = fmaxf(s[0] + b1v[0], 0.f), v1 = fmaxf(s[1] + b1v[1], 0.f);
      float v2 = fmaxf(s[2] + b1v[2], 0.f), v3 = fmaxf(s[3] + b1v[3], 0.f);
      uint2 w;
      w.x = (unsigned)f2bf(v0) | ((unsigned)f2bf(v1) << 16);
      w.y = (unsigned)f2bf(v2) | ((unsigned)f2bf(v3) << 16);
      *(uint2*)&Pw[l16*72 + nt*16 + quad*4] = w;   // P[act=l16][dff], packed b64
    }
    asm volatile("s_waitcnt lgkmcnt(0)" ::: "memory");

    // phase 2: O += P @ W2c^T  (unchanged from R7)
    bf16x8 pf[2];
    #pragma unroll
    for (int kk = 0; kk < 2; ++kk)
      pf[kk] = *(const bf16x8*)&Pw[l16*72 + kk*32 + quad*8];
    #pragma unroll
    for (int nt = 0; nt < 8; ++nt){
      int row = nt*16 + l16;                       // output-col row of W2
      bf16x8 wf[2];
      #pragma unroll
      for (int kk = 0; kk < 2; ++kk)
        wf[kk] = *(const bf16x8*)&W2l[buf][(row*8 + ((kk*4 + quad) ^ (l16 & 7)))*8];
      #pragma unroll
      for (int kk = 0; kk < 2; ++kk)
        O[nt] = __builtin_amdgcn_mfma_f32_16x16x32_bf16(pf[kk], wf[kk], O[nt], 0, 0, 0);
    }

    if (c + 1 < 32){
      asm volatile("s_waitcnt vmcnt(0)" ::: "memory");
      __syncthreads();
    }
  }

  epilogue_ln64(O, m0, wave, quad, l16, b2, g, beta, cur, curb);
}

// ---------------- final masked mean, two-stage ----------------
__global__ __launch_bounds__(128) void reduce1_kernel(
    const float* __restrict__ cur, const float* __restrict__ mask,
    float* __restrict__ partial, float* __restrict__ cnt)
{
  int b = blockIdx.x, c = blockIdx.y, t = threadIdx.x;
  float acc = 0.f, cn = 0.f;
  for (int s = c*128; s < c*128 + 128; ++s){
    float mk = mask[b*NPER + s];
    acc += cur[(size_t)(b*NPER + s)*DD + t] * mk;
    cn += mk;
  }
  partial[(size_t)(b*8 + c)*DD + t] = acc;
  if (t == 0) cnt[b*8 + c] = cn;
}
__global__ __launch_bounds__(128) void reduce2_kernel(
    const float* __restrict__ partial, const float* __restrict__ cnt,
    const int* __restrict__ flag, void* __restrict__ out)
{
  int b = blockIdx.x, t = threadIdx.x;
  float acc = 0.f, cn = 0.f;
  #pragma unroll
  for (int c = 0; c < 8; ++c){
    acc += partial[(size_t)(b*8 + c)*DD + t];
    cn  += cnt[b*8 + c];
  }
  float val = acc / cn;
  if (*flag) ((u16*)out)[b*DD + t] = f2bf(val);
  else       ((float*)out)[b*DD + t] = val;
}

// ---------------- host ----------------
extern "C" void kernel_launch(void* const* d_in, const int* in_sizes, int n_in,
                              void* d_out, int out_size, void* d_ws, size_t ws_size,
                              hipStream_t stream)
{
  (void)in_sizes; (void)n_in; (void)out_size; (void)ws_size;
  char* ws = (char*)d_ws;
  int*   flag   = (int*)(ws + OFF_FLAG);
  int*   starts = (int*)(ws + OFF_STARTS);
  float* BIN  = (float*)(ws + OFF_BIN);
  float* BQKV = (float*)(ws + OFF_BQKV);
  float* BO   = (float*)(ws + OFF_BO);
  float* B1   = (float*)(ws + OFF_B1);
  float* B2   = (float*)(ws + OFF_B2);
  float* LN1G = (float*)(ws + OFF_LN1G);
  float* LN1B = (float*)(ws + OFF_LN1B);
  float* LN2G = (float*)(ws + OFF_LN2G);
  float* LN2B = (float*)(ws + OFF_LN2B);
  u16* XB    = (u16*)(ws + OFF_XB);
  u16* WINB  = (u16*)(ws + OFF_WINB);
  u16* WQKVB = (u16*)(ws + OFF_WQKVB);
  u16* WOB   = (u16*)(ws + OFF_WOB);
  u16* W1B   = (u16*)(ws + OFF_W1B);
  u16* W2B   = (u16*)(ws + OFF_W2B);
  float* CUR = (float*)(ws + OFF_CUR);
  float* TMP = (float*)(ws + OFF_TMP);
  u16* CURB  = (u16*)(ws + OFF_CURB);
  u16* QKVB  = (u16*)(ws + OFF_QKVB);
  u16* ATTNOB= (u16*)(ws + OFF_ATTNOB);
  float* MASK= (float*)(ws + OFF_MASK);
  u16* VT    = (u16*)(ws + OFF_VT);
  float* RED = (float*)(ws + OFF_RED);
  float* CNT = (float*)(ws + OFF_CNT);

  detect_kernel<<<1, 256, 0, stream>>>((const unsigned*)d_in[0], flag);
  starts_kernel<<<1, 64, 0, stream>>>((const int*)d_in[1], starts);

  ConvArgs ca;
  ca.s[0]  = { d_in[0],  XB,    NTOT*INDIM, 1 };
  ca.s[1]  = { d_in[2],  WINB,  DD*INDIM,   1 };
  ca.s[2]  = { d_in[4],  WQKVB, LL*3*DD*DD, 1 };
  ca.s[3]  = { d_in[6],  WOB,   LL*DD*DD,   1 };
  ca.s[4]  = { d_in[8],  W1B,   LL*DFF*DD,  1 };
  ca.s[5]  = { d_in[10], W2B,   LL*DD*DFF,  1 };
  ca.s[6]  = { d_in[3],  BIN,   DD,         0 };
  ca.s[7]  = { d_in[5],  BQKV,  LL*3*DD,    0 };
  ca.s[8]  = { d_in[7],  BO,    LL*DD,      0 };
  ca.s[9]  = { d_in[9],  B1,    LL*DFF,     0 };
  ca.s[10] = { d_in[11], B2,    LL*DD,      0 };
  ca.s[11] = { d_in[12], LN1G,  LL*DD,      0 };
  ca.s[12] = { d_in[13], LN1B,  LL*DD,      0 };
  ca.s[13] = { d_in[14], LN2G,  LL*DD,      0 };
  ca.s[14] = { d_in[15], LN2B,  LL*DD,      0 };
  int nblk = 0;
  for (int i = 0; i < 15; ++i) nblk += (ca.s[i].n + 1023) >> 10;
  convall_kernel<<<nblk, 256, 0, stream>>>(ca, flag);

  gemm_bf16<<<dim3(NTOT/64, DD/64), 256, 0, stream>>>(
      XB, INDIM, WINB, INDIM, BIN, TMP, nullptr, DD, INDIM, 0);
  scatter_kernel<<<NTOT, 128, 0, stream>>>(TMP, (const int*)d_in[1], starts, CUR, CURB, MASK);

  for (int l = 0; l < LL; ++l){
    wgemm_kernel<<<dim3(NTOT/64, 3), 256, 0, stream>>>(
        CURB, WQKVB + (size_t)l*3*DD*DD, BQKV + l*3*DD, 0,
        QKVB, 384, VT, nullptr, nullptr, nullptr, nullptr);
    fattn_kernel<<<dim3(NPER/128, HH, BB), 256, 0, stream>>>(QKVB, VT, ATTNOB);
    wgemm_kernel<<<dim3(NTOT/64, 1), 256, 0, stream>>>(
        ATTNOB, WOB + (size_t)l*DD*DD, BO + l*DD, 1,
        nullptr, 0, nullptr, CUR, CURB, LN1G + l*DD, LN1B + l*DD);
    ffn_kernel<<<dim3(NTOT/64), 256, 0, stream>>>(
        CURB, W1B + (size_t)l*DFF*DD, W2B + (size_t)l*DD*DFF,
        B1 + l*DFF, B2 + l*DD, LN2G + l*DD, LN2B + l*DD, CUR, CURB);
  }

  reduce1_kernel<<<dim3(BB, 8), 128, 0, stream>>>(CUR, MASK, RED, CNT);
  reduce2_kernel<<<BB, 128, 0, stream>>>(RED, CNT, flag, d_out);
}

// Round 12
// 493.348 us; speedup vs baseline: 1.1524x; 1.0293x over previous
//
#include <hip/hip_runtime.h>
#include <hip/hip_bf16.h>
#include <stdint.h>

// ---------------- static problem sizes ----------------
#define BB    32
#define NPER  1024
#define NTOT  32768
#define DD    128
#define HH    4
#define HD    32
#define LL    3
#define DFF   2048
#define INDIM 64
#define QKSCALE 0.17677669529663687f

typedef unsigned short u16;
typedef short bf16x8 __attribute__((ext_vector_type(8)));   // 8 bf16 (4 VGPRs)
typedef float f32x4 __attribute__((ext_vector_type(4)));

// address-space casts for global_load_lds (direct global->LDS DMA)
#define AS_GLOBAL(p) ((const __attribute__((address_space(1))) void*)(p))
#define AS_LDS(p)    ((__attribute__((address_space(3))) void*)(p))

__device__ __forceinline__ float bf2f(u16 v){
  unsigned u = ((unsigned)v) << 16; float f; __builtin_memcpy(&f, &u, 4); return f;
}
__device__ __forceinline__ u16 f2bf(float f){
  unsigned u; __builtin_memcpy(&u, &f, 4);
  unsigned lsb = (u >> 16) & 1u;
  u += 0x7fffu + lsb;              // round-to-nearest-even
  return (u16)(u >> 16);
}

// ---------------- workspace layout (bytes) ----------------
constexpr size_t OFF_FLAG   = 0;
constexpr size_t OFF_STARTS = 256;
constexpr size_t OFF_BIN    = 1024;
constexpr size_t OFF_BQKV   = OFF_BIN   + 128*4;
constexpr size_t OFF_BO     = OFF_BQKV  + 1152*4;
constexpr size_t OFF_B1     = OFF_BO    + 384*4;
constexpr size_t OFF_B2     = OFF_B1    + 6144*4;
constexpr size_t OFF_LN1G   = OFF_B2    + 384*4;
constexpr size_t OFF_LN1B   = OFF_LN1G  + 384*4;
constexpr size_t OFF_LN2G   = OFF_LN1B  + 384*4;
constexpr size_t OFF_LN2B   = OFF_LN2G  + 384*4;
constexpr size_t OFF_XB     = 40960;
constexpr size_t OFF_WINB   = OFF_XB    + (size_t)2097152*2;
constexpr size_t OFF_WQKVB  = OFF_WINB  + (size_t)8192*2;
constexpr size_t OFF_WOB    = OFF_WQKVB + (size_t)147456*2;
constexpr size_t OFF_W1B    = OFF_WOB   + (size_t)49152*2;
constexpr size_t OFF_W2B    = OFF_W1B   + (size_t)786432*2;
constexpr size_t OFF_CUR    = OFF_W2B   + (size_t)786432*2;
constexpr size_t OFF_TMP    = OFF_CUR   + (size_t)4194304*4;      // (unused)
constexpr size_t OFF_CURB   = OFF_TMP   + (size_t)4194304*4;
constexpr size_t OFF_QKVB   = OFF_CURB  + (size_t)4194304*2;
constexpr size_t OFF_ATTNOB = OFF_QKVB  + (size_t)12582912*2;
constexpr size_t OFF_ACTB   = OFF_ATTNOB+ (size_t)4194304*2;      // (unused)
constexpr size_t OFF_MASK   = OFF_ACTB  + (size_t)16777216*2;
constexpr size_t OFF_VT     = OFF_MASK  + (size_t)NTOT*4;
constexpr size_t OFF_RED    = OFF_VT    + (size_t)4096*1024*2;
constexpr size_t OFF_CNT    = OFF_RED   + (size_t)32*8*128*4;

// ---------------- dtype detection ----------------
__device__ __forceinline__ int plaus(unsigned bits){
  if ((bits << 1) == 0u) return 1;
  unsigned e = (bits >> 23) & 0xFFu;
  return (e >= 100u && e <= 140u) ? 1 : 0;
}
__global__ void detect_kernel(const unsigned* __restrict__ x, int* __restrict__ flag){
  __shared__ int red[256];
  int t = threadIdx.x, c = 0;
  for (int i = t; i < 2048; i += 256){
    unsigned w = x[i];
    c += (plaus(w << 16) & plaus(w & 0xFFFF0000u));
  }
  red[t] = c; __syncthreads();
  for (int s = 128; s > 0; s >>= 1){ if (t < s) red[t] += red[t+s]; __syncthreads(); }
  if (t == 0) *flag = (red[0] >= 1229) ? 1 : 0;
}

__global__ void starts_kernel(const int* __restrict__ batch, int* __restrict__ starts){
  int b = threadIdx.x;
  if (b < BB){
    int lo = 0, hi = NTOT;
    while (lo < hi){ int mid = (lo + hi) >> 1; if (batch[mid] < b) lo = mid + 1; else hi = mid; }
    starts[b] = lo;
  }
}

// ---------------- fused conversion of all 15 float tensors (1 launch) ----------------
struct ConvSeg { const void* src; void* dst; int n; int tobf; };
struct ConvArgs { ConvSeg s[15]; };

__global__ __launch_bounds__(256) void convall_kernel(ConvArgs a, const int* __restrict__ flag){
  const int isb = *flag;
  const int blk = blockIdx.x;
  int seg = -1, base = 0, lb = 0;
  #pragma unroll
  for (int i = 0; i < 15; ++i){
    int nb = (a.s[i].n + 1023) >> 10;
    if (seg < 0){
      if (blk < base + nb){ seg = i; lb = blk - base; }
      base += nb;
    }
  }
  const ConvSeg sg = a.s[seg];
  const int idx = lb*1024 + threadIdx.x*4;
  if (idx >= sg.n) return;
  if (sg.tobf){
    u16* dst = (u16*)sg.dst + idx;
    if (isb){
      *(uint2*)dst = *(const uint2*)((const u16*)sg.src + idx);
    } else {
      const float* s4 = (const float*)sg.src + idx;
      dst[0] = f2bf(s4[0]); dst[1] = f2bf(s4[1]);
      dst[2] = f2bf(s4[2]); dst[3] = f2bf(s4[3]);
    }
  } else {
    float* dst = (float*)sg.dst + idx;
    if (isb){
      const u16* s4 = (const u16*)sg.src + idx;
      dst[0] = bf2f(s4[0]); dst[1] = bf2f(s4[1]);
      dst[2] = bf2f(s4[2]); dst[3] = bf2f(s4[3]);
    } else {
      *(float4*)dst = *(const float4*)((const float*)sg.src + idx);
    }
  }
}

// ---------------- fused input projection + scatter + mask ----------------
// h = x @ W_in^T + b_in, scattered to padded (cur, curb), mask = (rowsum != 0).
// 64-row blocks (grid 512), W_in (128x64, 16 KB) staged in LDS with the
// ffn-W2l swizzle (row stride 64, 8 chunks -- identical pattern).
__global__ __launch_bounds__(256) void inproj_kernel(
    const u16* __restrict__ XB,       // [NTOT][64] bf16
    const u16* __restrict__ WINB,     // [128][64] bf16
    const float* __restrict__ bin,    // [128]
    const int* __restrict__ batch, const int* __restrict__ starts,
    float* __restrict__ cur, u16* __restrict__ curb, float* __restrict__ mask)
{
  __shared__ __align__(16) u16 Wl[8192];           // 128 rows x 64 k, XOR8 swizzle
  const int t = threadIdx.x, wave = t >> 6, lane = t & 63;
  const int quad = lane >> 4, l16 = lane & 15;
  const int m0 = blockIdx.x * 64;

  // stage: slot s -> row r=s>>3, chunk c8=(s&7)^(r&7)
  #pragma unroll
  for (int j = 0; j < 4; ++j){
    int s = t + 256*j;
    int r = s >> 3, c8 = (s & 7) ^ (r & 7);
    *(uint4*)&Wl[s*8] = *(const uint4*)(WINB + (size_t)r*INDIM + c8*8);
  }
  bf16x8 af[2];
  #pragma unroll
  for (int kk = 0; kk < 2; ++kk)
    af[kk] = *(const bf16x8*)(XB + (size_t)(m0 + wave*16 + l16)*INDIM + kk*32 + quad*8);
  __syncthreads();

  f32x4 O[8];
  #pragma unroll
  for (int nt = 0; nt < 8; ++nt){ O[nt][0]=0.f; O[nt][1]=0.f; O[nt][2]=0.f; O[nt][3]=0.f; }

  #pragma unroll
  for (int nt = 0; nt < 8; ++nt){
    int row = nt*16 + l16;                         // output col
    bf16x8 wf[2];
    #pragma unroll
    for (int kk = 0; kk < 2; ++kk)
      wf[kk] = *(const bf16x8*)&Wl[(row*8 + ((kk*4 + quad) ^ (row & 7)))*8];
    #pragma unroll
    for (int kk = 0; kk < 2; ++kk)
      O[nt] = __builtin_amdgcn_mfma_f32_16x16x32_bf16(af[kk], wf[kk], O[nt], 0, 0, 0);
  }

  // epilogue: bias, rowsum (mask), scatter by (graph, pos)
  #pragma unroll
  for (int rr = 0; rr < 4; ++rr){
    int node = m0 + wave*16 + quad*4 + rr;
    int gr = batch[node];
    int p  = node - starts[gr];
    float vs[8], sum = 0.f;
    #pragma unroll
    for (int nt = 0; nt < 8; ++nt){
      float v = O[nt][rr] + bin[nt*16 + l16];
      vs[nt] = v; sum += v;
    }
    sum += __shfl_xor(sum, 1); sum += __shfl_xor(sum, 2);
    sum += __shfl_xor(sum, 4); sum += __shfl_xor(sum, 8);
    if ((unsigned)p < (unsigned)NPER && (unsigned)gr < (unsigned)BB){
      size_t j = (size_t)gr*NPER + p;
      #pragma unroll
      for (int nt = 0; nt < 8; ++nt){
        int col = nt*16 + l16;
        cur[j*DD + col]  = vs[nt];
        curb[j*DD + col] = f2bf(vs[nt]);
      }
      if (l16 == 0) mask[j] = (sum != 0.f) ? 1.f : 0.f;
    }
  }
}

// ---------------- MFMA flash attention v3: 32 q-rows per wave ----------------
__global__ __launch_bounds__(256) void fattn_kernel(
    const u16* __restrict__ qkvb,   // [NTOT][384]
    const u16* __restrict__ vt,     // [B*H*HD][NPER]
    u16* __restrict__ attnob)       // [NTOT][128]
{
  __shared__ __align__(16) u16 Klds[2][2048];      // [c(4)][r(64)][8]
  __shared__ __align__(16) u16 Vl[2][2048];        // [cv(8)][d(32)][8]
  __shared__ __align__(16) u16 Pl[4][2][16*72];    // per-(wave,qt) P [q][s], pitch 72

  const int t = threadIdx.x;
  const int wave = t >> 6, lane = t & 63;
  const int quad = lane >> 4, l16 = lane & 15;
  const int q0 = blockIdx.x * 128;
  const int h = blockIdx.y, b = blockIdx.z;
  const size_t qkvbase = (size_t)b * NPER * 384;
  const u16* Kg = qkvb + qkvbase + 128 + h*HD;
  const u16* Vg = vt + (size_t)((b*HH + h)*HD) * NPER;

  bf16x8 qf[2];
  #pragma unroll
  for (int qt = 0; qt < 2; ++qt){
    const u16* qp = qkvb + qkvbase + (size_t)(q0 + wave*32 + qt*16 + l16)*384 + h*HD + quad*8;
    uint4 qv = *(const uint4*)qp;
    u16 raw[8]; __builtin_memcpy(raw, &qv, 16);
    #pragma unroll
    for (int j = 0; j < 8; ++j) qf[qt][j] = (short)f2bf(bf2f(raw[j]) * QKSCALE);
  }

  const int vcv = wave*2 + (lane >> 5), vd = lane & 31;
  auto stage = [&](int buf, int kt){
    __builtin_amdgcn_global_load_lds(
        AS_GLOBAL(Kg + (size_t)(kt*64 + lane)*384 + wave*8),
        AS_LDS(&Klds[buf][wave*64*8]), 16, 0, 0);
    __builtin_amdgcn_global_load_lds(
        AS_GLOBAL(Vg + (size_t)vd*NPER + kt*64 + vcv*8),
        AS_LDS(&Vl[buf][wave*64*8]), 16, 0, 0);
  };

  float lsum[2] = {0.f, 0.f};
  f32x4 o[2][2];
  #pragma unroll
  for (int qt = 0; qt < 2; ++qt)
    #pragma unroll
    for (int i = 0; i < 2; ++i){ o[qt][i][0]=0.f; o[qt][i][1]=0.f; o[qt][i][2]=0.f; o[qt][i][3]=0.f; }

  stage(0, 0);
  asm volatile("s_waitcnt vmcnt(0)" ::: "memory");
  __syncthreads();

  for (int kt = 0; kt < 16; ++kt){
    const int buf = kt & 1;
    if (kt + 1 < 16) stage(buf ^ 1, kt + 1);

    f32x4 sfr[2][4];
    #pragma unroll
    for (int nt = 0; nt < 4; ++nt){
      bf16x8 kf = *(const bf16x8*)&Klds[buf][(quad*64 + nt*16 + l16)*8];
      f32x4 z = {0.f,0.f,0.f,0.f};
      sfr[0][nt] = __builtin_amdgcn_mfma_f32_16x16x32_bf16(kf, qf[0], z, 0, 0, 0);
      sfr[1][nt] = __builtin_amdgcn_mfma_f32_16x16x32_bf16(kf, qf[1], z, 0, 0, 0);
    }

    #pragma unroll
    for (int qt = 0; qt < 2; ++qt){
      float ps = 0.f;
      #pragma unroll
      for (int nt = 0; nt < 4; ++nt){
        float e0 = __expf(sfr[qt][nt][0]), e1 = __expf(sfr[qt][nt][1]);
        float e2 = __expf(sfr[qt][nt][2]), e3 = __expf(sfr[qt][nt][3]);
        ps += (e0 + e1) + (e2 + e3);
        uint2 w;
        w.x = (unsigned)f2bf(e0) | ((unsigned)f2bf(e1) << 16);
        w.y = (unsigned)f2bf(e2) | ((unsigned)f2bf(e3) << 16);
        *(uint2*)&Pl[wave][qt][l16*72 + nt*16 + quad*4] = w;
      }
      ps += __shfl_xor(ps, 16);
      ps += __shfl_xor(ps, 32);
      lsum[qt] += ps;
    }
    asm volatile("s_waitcnt lgkmcnt(0)" ::: "memory");

    #pragma unroll
    for (int kk = 0; kk < 2; ++kk){
      bf16x8 v0 = *(const bf16x8*)&Vl[buf][((kk*4 + quad)*32 + l16)*8];
      bf16x8 v1 = *(const bf16x8*)&Vl[buf][((kk*4 + quad)*32 + 16 + l16)*8];
      #pragma unroll
      for (int qt = 0; qt < 2; ++qt){
        bf16x8 pf = *(const bf16x8*)&Pl[wave][qt][l16*72 + kk*32 + quad*8];
        o[qt][0] = __builtin_amdgcn_mfma_f32_16x16x32_bf16(pf, v0, o[qt][0], 0, 0, 0);
        o[qt][1] = __builtin_amdgcn_mfma_f32_16x16x32_bf16(pf, v1, o[qt][1], 0, 0, 0);
      }
    }

    if (kt + 1 < 16){
      asm volatile("s_waitcnt vmcnt(0)" ::: "memory");
      __syncthreads();
    }
  }

  #pragma unroll
  for (int qt = 0; qt < 2; ++qt){
    #pragma unroll
    for (int r = 0; r < 4; ++r){
      float inv = 1.f / __shfl(lsum[qt], quad*4 + r);
      int row = q0 + wave*32 + qt*16 + quad*4 + r;
      size_t base = (size_t)(b*NPER + row)*DD + h*HD;
      attnob[base + l16]      = f2bf(o[qt][0][r] * inv);
      attnob[base + 16 + l16] = f2bf(o[qt][1][r] * inv);
    }
  }
}

// ---------------- LN epilogue (wave owns 16 rows): out = LN(resid + O + bias) ----------------
__device__ __forceinline__ void epilogue_ln64(
    const f32x4 O[8], int m0, int wave, int quad, int l16,
    const float* __restrict__ bias, const float* __restrict__ g,
    const float* __restrict__ beta, float* __restrict__ cur,
    u16* __restrict__ curb)
{
  #pragma unroll
  for (int rr = 0; rr < 4; ++rr){
    int row = m0 + wave*16 + quad*4 + rr;
    float vs[8], sum = 0.f;
    #pragma unroll
    for (int nt = 0; nt < 8; ++nt){
      int col = nt*16 + l16;
      float v = O[nt][rr] + bias[col] + cur[(size_t)row*DD + col];
      vs[nt] = v; sum += v;
    }
    sum += __shfl_xor(sum, 1); sum += __shfl_xor(sum, 2);
    sum += __shfl_xor(sum, 4); sum += __shfl_xor(sum, 8);
    float mean = sum * (1.f/DD);
    float sq = 0.f;
    #pragma unroll
    for (int nt = 0; nt < 8; ++nt){ float d = vs[nt] - mean; sq += d*d; }
    sq += __shfl_xor(sq, 1); sq += __shfl_xor(sq, 2);
    sq += __shfl_xor(sq, 4); sq += __shfl_xor(sq, 8);
    float rs = rsqrtf(sq * (1.f/DD) + 1e-5f);
    #pragma unroll
    for (int nt = 0; nt < 8; ++nt){
      int col = nt*16 + l16;
      float o = (vs[nt] - mean)*rs*g[col] + beta[col];
      cur[(size_t)row*DD + col]  = o;
      curb[(size_t)row*DD + col] = f2bf(o);
    }
  }
}

// ---------------- 64-row-block GEMM (Wo + LN1) ----------------
__global__ __launch_bounds__(256) void wgemm_kernel(
    const u16* __restrict__ A,        // [M][128] bf16
    const u16* __restrict__ Wbase,    // [128][128] bf16
    const float* __restrict__ biasb,  // [128]
    float* __restrict__ cur, u16* __restrict__ curb,
    const float* __restrict__ g, const float* __restrict__ beta)
{
  __shared__ __align__(16) u16 Wl[16384];          // 128x128, XOR-swizzled chunks
  const int t = threadIdx.x, wave = t >> 6, lane = t & 63;
  const int quad = lane >> 4, l16 = lane & 15;
  const int m0 = blockIdx.x * 64;

  #pragma unroll
  for (int j = 0; j < 8; ++j){
    int s = t + 256*j;
    int r = s >> 4, cx = (s & 15) ^ (r & 15);
    *(uint4*)&Wl[s*8] = *(const uint4*)(Wbase + (size_t)r*128 + cx*8);
  }
  bf16x8 af[4];
  #pragma unroll
  for (int kk = 0; kk < 4; ++kk)
    af[kk] = *(const bf16x8*)(A + (size_t)(m0 + wave*16 + l16)*128 + kk*32 + quad*8);
  __syncthreads();

  f32x4 O[8];
  #pragma unroll
  for (int nt = 0; nt < 8; ++nt){ O[nt][0]=0.f; O[nt][1]=0.f; O[nt][2]=0.f; O[nt][3]=0.f; }

  #pragma unroll
  for (int nt = 0; nt < 8; ++nt){
    int row = nt*16 + l16;
    bf16x8 wf[4];
    #pragma unroll
    for (int kk = 0; kk < 4; ++kk)
      wf[kk] = *(const bf16x8*)&Wl[(row*16 + ((kk*4 + quad) ^ l16))*8];
    #pragma unroll
    for (int kk = 0; kk < 4; ++kk)
      O[nt] = __builtin_amdgcn_mfma_f32_16x16x32_bf16(af[kk], wf[kk], O[nt], 0, 0, 0);
  }

  epilogue_ln64(O, m0, wave, quad, l16, biasb, g, beta, cur, curb);
}

// ---------------- QKV GEMM: 128-row blocks, wave owns 32 rows ----------------
// grid (NTOT/128, 3) = 768 blocks = 3/CU. W-fragment reads shared across the
// wave's 2 row-tiles (fattn-v3 trick): halves LDS W reads per MFMA vs wgemm.
// nb==2 (V slice) streams transposed into VT.
__global__ __launch_bounds__(256) void wgemm2_kernel(
    const u16* __restrict__ A,        // [M][128] bf16
    const u16* __restrict__ Wbase,    // [3*128][128] bf16
    const float* __restrict__ biasb,  // [3*128]
    u16* __restrict__ outb, int opitch,
    u16* __restrict__ vtout)
{
  __shared__ __align__(16) u16 Wl[16384];          // 128x128, XOR-swizzled chunks
  const int t = threadIdx.x, wave = t >> 6, lane = t & 63;
  const int quad = lane >> 4, l16 = lane & 15;
  const int m0 = blockIdx.x * 128, nb = blockIdx.y;
  const u16* Wsl = Wbase + (size_t)nb * 16384;
  const float* bias = biasb + nb * 128;

  #pragma unroll
  for (int j = 0; j < 8; ++j){
    int s = t + 256*j;
    int r = s >> 4, cx = (s & 15) ^ (r & 15);
    *(uint4*)&Wl[s*8] = *(const uint4*)(Wsl + (size_t)r*128 + cx*8);
  }
  bf16x8 af[2][4];
  #pragma unroll
  for (int mt = 0; mt < 2; ++mt)
    #pragma unroll
    for (int kk = 0; kk < 4; ++kk)
      af[mt][kk] = *(const bf16x8*)(A + (size_t)(m0 + wave*32 + mt*16 + l16)*128 + kk*32 + quad*8);
  __syncthreads();

  f32x4 O[2][8];
  #pragma unroll
  for (int mt = 0; mt < 2; ++mt)
    #pragma unroll
    for (int nt = 0; nt < 8; ++nt){ O[mt][nt][0]=0.f; O[mt][nt][1]=0.f; O[mt][nt][2]=0.f; O[mt][nt][3]=0.f; }

  #pragma unroll
  for (int nt = 0; nt < 8; ++nt){
    int row = nt*16 + l16;
    bf16x8 wf[4];
    #pragma unroll
    for (int kk = 0; kk < 4; ++kk)
      wf[kk] = *(const bf16x8*)&Wl[(row*16 + ((kk*4 + quad) ^ l16))*8];
    #pragma unroll
    for (int mt = 0; mt < 2; ++mt)
      #pragma unroll
      for (int kk = 0; kk < 4; ++kk)
        O[mt][nt] = __builtin_amdgcn_mfma_f32_16x16x32_bf16(af[mt][kk], wf[kk], O[mt][nt], 0, 0, 0);
  }

  if (nb == 2){
    #pragma unroll
    for (int mt = 0; mt < 2; ++mt){
      int rowb = m0 + wave*32 + mt*16 + quad*4;
      int bg = rowb >> 10, s = rowb & 1023;
      #pragma unroll
      for (int nt = 0; nt < 8; ++nt){
        int col = nt*16 + l16;
        int hh = col >> 5, d = col & 31;
        float v0 = O[mt][nt][0] + bias[col], v1 = O[mt][nt][1] + bias[col];
        float v2 = O[mt][nt][2] + bias[col], v3 = O[mt][nt][3] + bias[col];
        uint2 w;
        w.x = (unsigned)f2bf(v0) | ((unsigned)f2bf(v1) << 16);
        w.y = (unsigned)f2bf(v2) | ((unsigned)f2bf(v3) << 16);
        *(uint2*)(vtout + (size_t)((bg*HH + hh)*HD + d)*NPER + s) = w;
      }
    }
  } else {
    #pragma unroll
    for (int mt = 0; mt < 2; ++mt)
      #pragma unroll
      for (int rr = 0; rr < 4; ++rr){
        int row = m0 + wave*32 + mt*16 + quad*4 + rr;
        #pragma unroll
        for (int nt = 0; nt < 8; ++nt){
          int col = nt*16 + l16;
          outb[(size_t)row*opitch + nb*128 + col] = f2bf(O[mt][nt][rr] + bias[col]);
        }
      }
  }
}

// ---------------- fused FFN (R7 exact): 64-row blocks, dbuf W via DMA ----------------
__global__ __launch_bounds__(256, 2) void ffn_kernel(
    const u16* __restrict__ Ag,       // CURB [M][128]
    const u16* __restrict__ W1g,      // [2048][128]
    const u16* __restrict__ W2g,      // [128][2048]
    const float* __restrict__ b1,
    const float* __restrict__ b2,
    const float* __restrict__ g, const float* __restrict__ beta,
    float* __restrict__ cur, u16* __restrict__ curb)
{
  __shared__ __align__(16) u16 W1l[2][8192];       // 64x128 chunk, swizzled, x2 buf
  __shared__ __align__(16) u16 W2l[2][8192];       // 128x64 chunk, swizzled, x2 buf
  __shared__ __align__(16) u16 Pl[4][16*72];       // per-wave act, pitch 72

  const int t = threadIdx.x, wave = t >> 6, lane = t & 63;
  const int quad = lane >> 4, l16 = lane & 15;
  const int m0 = blockIdx.x * 64;
  u16* Pw = &Pl[wave][0];

  auto stage = [&](int buf, int dffc){
    #pragma unroll
    for (int i = 0; i < 4; ++i){
      const int s0 = wave*256 + i*64;
      const int s  = s0 + lane;
      { int r = s >> 4, cx = (s & 15) ^ (r & 15);
        __builtin_amdgcn_global_load_lds(
            AS_GLOBAL(W1g + (size_t)(dffc + r)*128 + cx*8),
            AS_LDS(&W1l[buf][s0*8]), 16, 0, 0); }
      { int r = s >> 3, cx = (s & 7) ^ (r & 7);
        __builtin_amdgcn_global_load_lds(
            AS_GLOBAL(W2g + (size_t)r*DFF + dffc + cx*8),
            AS_LDS(&W2l[buf][s0*8]), 16, 0, 0); }
    }
  };

  bf16x8 af[4];
  #pragma unroll
  for (int kk = 0; kk < 4; ++kk)
    af[kk] = *(const bf16x8*)(Ag + (size_t)(m0 + wave*16 + l16)*128 + kk*32 + quad*8);

  f32x4 O[8];
  #pragma unroll
  for (int nt = 0; nt < 8; ++nt){ O[nt][0]=0.f; O[nt][1]=0.f; O[nt][2]=0.f; O[nt][3]=0.f; }

  stage(0, 0);
  asm volatile("s_waitcnt vmcnt(0)" ::: "memory");
  __syncthreads();

  for (int c = 0; c < 32; ++c){
    const int buf = c & 1;
    if (c + 1 < 32) stage(buf ^ 1, (c + 1)*64);

    // phase 1: act = relu(A @ W1c^T + b1) -> P (wave-private, bf16)
    #pragma unroll
    for (int nt = 0; nt < 4; ++nt){
      int row = nt*16 + l16;
      bf16x8 wf[4];
      #pragma unroll
      for (int kk = 0; kk < 4; ++kk)
        wf[kk] = *(const bf16x8*)&W1l[buf][(row*16 + ((kk*4 + quad) ^ l16))*8];
      float b1v = b1[c*64 + row];
      f32x4 s = {0.f,0.f,0.f,0.f};
      #pragma unroll
      for (int kk = 0; kk < 4; ++kk)
        s = __builtin_amdgcn_mfma_f32_16x16x32_bf16(af[kk], wf[kk], s, 0, 0, 0);
      #pragma unroll
      for (int rr = 0; rr < 4; ++rr)
        Pw[(quad*4 + rr)*72 + nt*16 + l16] = f2bf(fmaxf(s[rr] + b1v, 0.f));
    }
    asm volatile("s_waitcnt lgkmcnt(0)" ::: "memory");

    // phase 2: O += P @ W2c^T
    bf16x8 pf[2];
    #pragma unroll
    for (int kk = 0; kk < 2; ++kk)
      pf[kk] = *(const bf16x8*)&Pw[l16*72 + kk*32 + quad*8];
    #pragma unroll
    for (int nt = 0; nt < 8; ++nt){
      int row = nt*16 + l16;
      bf16x8 wf[2];
      #pragma unroll
      for (int kk = 0; kk < 2; ++kk)
        wf[kk] = *(const bf16x8*)&W2l[buf][(row*8 + ((kk*4 + quad) ^ (l16 & 7)))*8];
      #pragma unroll
      for (int kk = 0; kk < 2; ++kk)
        O[nt] = __builtin_amdgcn_mfma_f32_16x16x32_bf16(pf[kk], wf[kk], O[nt], 0, 0, 0);
    }

    if (c + 1 < 32){
      asm volatile("s_waitcnt vmcnt(0)" ::: "memory");
      __syncthreads();
    }
  }

  epilogue_ln64(O, m0, wave, quad, l16, b2, g, beta, cur, curb);
}

// ---------------- final masked mean, two-stage ----------------
__global__ __launch_bounds__(128) void reduce1_kernel(
    const float* __restrict__ cur, const float* __restrict__ mask,
    float* __restrict__ partial, float* __restrict__ cnt)
{
  int b = blockIdx.x, c = blockIdx.y, t = threadIdx.x;
  float acc = 0.f, cn = 0.f;
  for (int s = c*128; s < c*128 + 128; ++s){
    float mk = mask[b*NPER + s];
    acc += cur[(size_t)(b*NPER + s)*DD + t] * mk;
    cn += mk;
  }
  partial[(size_t)(b*8 + c)*DD + t] = acc;
  if (t == 0) cnt[b*8 + c] = cn;
}
__global__ __launch_bounds__(128) void reduce2_kernel(
    const float* __restrict__ partial, const float* __restrict__ cnt,
    const int* __restrict__ flag, void* __restrict__ out)
{
  int b = blockIdx.x, t = threadIdx.x;
  float acc = 0.f, cn = 0.f;
  #pragma unroll
  for (int c = 0; c < 8; ++c){
    acc += partial[(size_t)(b*8 + c)*DD + t];
    cn  += cnt[b*8 + c];
  }
  float val = acc / cn;
  if (*flag) ((u16*)out)[b*DD + t] = f2bf(val);
  else       ((float*)out)[b*DD + t] = val;
}

// ---------------- host ----------------
extern "C" void kernel_launch(void* const* d_in, const int* in_sizes, int n_in,
                              void* d_out, int out_size, void* d_ws, size_t ws_size,
                              hipStream_t stream)
{
  (void)in_sizes; (void)n_in; (void)out_size; (void)ws_size;
  char* ws = (char*)d_ws;
  int*   flag   = (int*)(ws + OFF_FLAG);
  int*   starts = (int*)(ws + OFF_STARTS);
  float* BIN  = (float*)(ws + OFF_BIN);
  float* BQKV = (float*)(ws + OFF_BQKV);
  float* BO   = (float*)(ws + OFF_BO);
  float* B1   = (float*)(ws + OFF_B1);
  float* B2   = (float*)(ws + OFF_B2);
  float* LN1G = (float*)(ws + OFF_LN1G);
  float* LN1B = (float*)(ws + OFF_LN1B);
  float* LN2G = (float*)(ws + OFF_LN2G);
  float* LN2B = (float*)(ws + OFF_LN2B);
  u16* XB    = (u16*)(ws + OFF_XB);
  u16* WINB  = (u16*)(ws + OFF_WINB);
  u16* WQKVB = (u16*)(ws + OFF_WQKVB);
  u16* WOB   = (u16*)(ws + OFF_WOB);
  u16* W1B   = (u16*)(ws + OFF_W1B);
  u16* W2B   = (u16*)(ws + OFF_W2B);
  float* CUR = (float*)(ws + OFF_CUR);
  u16* CURB  = (u16*)(ws + OFF_CURB);
  u16* QKVB  = (u16*)(ws + OFF_QKVB);
  u16* ATTNOB= (u16*)(ws + OFF_ATTNOB);
  float* MASK= (float*)(ws + OFF_MASK);
  u16* VT    = (u16*)(ws + OFF_VT);
  float* RED = (float*)(ws + OFF_RED);
  float* CNT = (float*)(ws + OFF_CNT);

  detect_kernel<<<1, 256, 0, stream>>>((const unsigned*)d_in[0], flag);
  starts_kernel<<<1, 64, 0, stream>>>((const int*)d_in[1], starts);

  ConvArgs ca;
  ca.s[0]  = { d_in[0],  XB,    NTOT*INDIM, 1 };
  ca.s[1]  = { d_in[2],  WINB,  DD*INDIM,   1 };
  ca.s[2]  = { d_in[4],  WQKVB, LL*3*DD*DD, 1 };
  ca.s[3]  = { d_in[6],  WOB,   LL*DD*DD,   1 };
  ca.s[4]  = { d_in[8],  W1B,   LL*DFF*DD,  1 };
  ca.s[5]  = { d_in[10], W2B,   LL*DD*DFF,  1 };
  ca.s[6]  = { d_in[3],  BIN,   DD,         0 };
  ca.s[7]  = { d_in[5],  BQKV,  LL*3*DD,    0 };
  ca.s[8]  = { d_in[7],  BO,    LL*DD,      0 };
  ca.s[9]  = { d_in[9],  B1,    LL*DFF,     0 };
  ca.s[10] = { d_in[11], B2,    LL*DD,      0 };
  ca.s[11] = { d_in[12], LN1G,  LL*DD,      0 };
  ca.s[12] = { d_in[13], LN1B,  LL*DD,      0 };
  ca.s[13] = { d_in[14], LN2G,  LL*DD,      0 };
  ca.s[14] = { d_in[15], LN2B,  LL*DD,      0 };
  int nblk = 0;
  for (int i = 0; i < 15; ++i) nblk += (ca.s[i].n + 1023) >> 10;
  convall_kernel<<<nblk, 256, 0, stream>>>(ca, flag);

  // fused input projection + scatter + mask
  inproj_kernel<<<NTOT/64, 256, 0, stream>>>(
      XB, WINB, BIN, (const int*)d_in[1], starts, CUR, CURB, MASK);

  for (int l = 0; l < LL; ++l){
    // QKV (wave owns 32 rows; V slice streams transposed into VT)
    wgemm2_kernel<<<dim3(NTOT/128, 3), 256, 0, stream>>>(
        CURB, WQKVB + (size_t)l*3*DD*DD, BQKV + l*3*DD, QKVB, 384, VT);
    fattn_kernel<<<dim3(NPER/128, HH, BB), 256, 0, stream>>>(QKVB, VT, ATTNOB);
    // Wo + residual + LN1
    wgemm_kernel<<<dim3(NTOT/64), 256, 0, stream>>>(
        ATTNOB, WOB + (size_t)l*DD*DD, BO + l*DD, CUR, CURB, LN1G + l*DD, LN1B + l*DD);
    // fused FFN + residual + LN2 (R7 structure)
    ffn_kernel<<<dim3(NTOT/64), 256, 0, stream>>>(
        CURB, W1B + (size_t)l*DFF*DD, W2B + (size_t)l*DD*DFF,
        B1 + l*DFF, B2 + l*DD, LN2G + l*DD, LN2B + l*DD, CUR, CURB);
  }

  reduce1_kernel<<<dim3(BB, 8), 128, 0, stream>>>(CUR, MASK, RED, CNT);
  reduce2_kernel<<<BB, 128, 0, stream>>>(RED, CNT, flag, d_out);
}